// Round 1
// baseline (3664.171 us; speedup 1.0000x reference)
//
#include <hip/hip_runtime.h>

#define NN 50000
#define NE 800000
#define HID 128

// ---------------- CSR build ----------------
__global__ void k_zero(int* cnt, int* cur, int n) {
  int i = blockIdx.x * blockDim.x + threadIdx.x;
  if (i < n) { cnt[i] = 0; cur[i] = 0; }
}

__global__ void k_count(const int* dst, int* cnt, int e) {
  int i = blockIdx.x * blockDim.x + threadIdx.x;
  if (i < e) atomicAdd(&cnt[dst[i]], 1);
}

// per-block exclusive scan (256-wide), block totals to bsum
__global__ void k_scan1(const int* cnt, int* offs, int* bsum, int n) {
  __shared__ int s[256];
  int i = blockIdx.x * 256 + threadIdx.x;
  int v = (i < n) ? cnt[i] : 0;
  s[threadIdx.x] = v;
  __syncthreads();
  #pragma unroll
  for (int d = 1; d < 256; d <<= 1) {
    int t = (threadIdx.x >= d) ? s[threadIdx.x - d] : 0;
    __syncthreads();
    s[threadIdx.x] += t;
    __syncthreads();
  }
  if (i < n) offs[i] = s[threadIdx.x] - v;
  if (threadIdx.x == 255) bsum[blockIdx.x] = s[255];
}

// scan the (<=256) block sums; bsum becomes exclusive offsets; *offsN = total
__global__ void k_scan2(int* bsum, int* offsN, int nb) {
  __shared__ int s[256];
  int v = (threadIdx.x < nb) ? bsum[threadIdx.x] : 0;
  s[threadIdx.x] = v;
  __syncthreads();
  #pragma unroll
  for (int d = 1; d < 256; d <<= 1) {
    int t = (threadIdx.x >= d) ? s[threadIdx.x - d] : 0;
    __syncthreads();
    s[threadIdx.x] += t;
    __syncthreads();
  }
  if (threadIdx.x < nb) bsum[threadIdx.x] = s[threadIdx.x] - v;
  if (threadIdx.x == 255) *offsN = s[255];
}

__global__ void k_scan3(int* offs, const int* bsum, int n) {
  int i = blockIdx.x * blockDim.x + threadIdx.x;
  if (i < n) offs[i] += bsum[i >> 8];
}

__global__ void k_dinv(const int* cnt, float* dinv, int n) {
  int i = blockIdx.x * blockDim.x + threadIdx.x;
  if (i < n) dinv[i] = rsqrtf((float)(cnt[i] + 1));
}

__global__ void k_fill(const int* src, const int* dst, const int* offs,
                       int* cur, int* adj, int e) {
  int i = blockIdx.x * blockDim.x + threadIdx.x;
  if (i < e) {
    int d = dst[i];
    int pos = atomicAdd(&cur[d], 1);
    adj[offs[d] + pos] = src[i];
  }
}

// ---------------- node GEMM: out[r][c] = dinv[r] * sum_k X[r][k]*W[k][c] ----
// blockDim = 128 (one thread per output col), 4 rows per block
template <int K>
__global__ void k_gemm(const float* __restrict__ X, const float* __restrict__ W,
                       const float* __restrict__ dinv, float* __restrict__ out,
                       int n) {
  const int ROWS = 4;
  __shared__ float xs[ROWS][K];
  int r0 = blockIdx.x * ROWS;
  int col = threadIdx.x;
  for (int idx = threadIdx.x; idx < ROWS * K; idx += 128) {
    int r = idx / K, k = idx % K;
    int gr = r0 + r;
    xs[r][k] = (gr < n) ? X[(size_t)gr * K + k] : 0.f;
  }
  __syncthreads();
  float acc[ROWS] = {0.f, 0.f, 0.f, 0.f};
  #pragma unroll
  for (int k = 0; k < K; k++) {
    float w = W[k * 128 + col];
    #pragma unroll
    for (int r = 0; r < ROWS; r++) acc[r] += xs[r][k] * w;
  }
  #pragma unroll
  for (int r = 0; r < ROWS; r++) {
    int gr = r0 + r;
    if (gr < n) out[(size_t)gr * 128 + col] = acc[r] * dinv[gr];
  }
}

// ---------------- aggregation: h[v] = relu(dinv[v]*(g[v] + sum g[src]) + b) --
// one wave (64 lanes) per node, float2 per lane over 128 dims
__global__ void k_agg(const float* __restrict__ g, const int* __restrict__ offs,
                      const int* __restrict__ adj, const float* __restrict__ dinv,
                      const float* __restrict__ bias, float* __restrict__ out,
                      int n) {
  int node = blockIdx.x * (blockDim.x >> 6) + (threadIdx.x >> 6);
  if (node >= n) return;
  int lane = threadIdx.x & 63;
  const float2* gp = (const float2*)(g + (size_t)node * 128);
  float2 acc = gp[lane];
  int s = offs[node], e = offs[node + 1];
  for (int i = s; i < e; i++) {
    int src = adj[i];
    float2 v = ((const float2*)(g + (size_t)src * 128))[lane];
    acc.x += v.x;
    acc.y += v.y;
  }
  float dv = dinv[node];
  float bx = bias[lane * 2], by = bias[lane * 2 + 1];
  float2 o;
  o.x = fmaxf(dv * acc.x + bx, 0.f);
  o.y = fmaxf(dv * acc.y + by, 0.f);
  ((float2*)(out + (size_t)node * 128))[lane] = o;
}

// ---------------- PQ: PQ[v][0:32] = h@Wa, PQ[v][32:64] = h@Wb ---------------
// blockDim 64 (one thread per output col of the fused 64-wide), 8 rows/block
__global__ void k_pq(const float* __restrict__ H, const float* __restrict__ We,
                     float* __restrict__ PQ, int n) {
  const int ROWS = 8;
  __shared__ float hs[ROWS][128];
  int r0 = blockIdx.x * ROWS;
  int c = threadIdx.x;  // 0..63
  for (int idx = threadIdx.x; idx < ROWS * 128; idx += 64) {
    int r = idx >> 7, k = idx & 127;
    int gr = r0 + r;
    hs[r][k] = (gr < n) ? H[(size_t)gr * 128 + k] : 0.f;
  }
  __syncthreads();
  float acc[ROWS];
  #pragma unroll
  for (int r = 0; r < ROWS; r++) acc[r] = 0.f;
  const float* Wbase = (c < 32) ? (We + c) : (We + 128 * 32 + (c - 32));
  #pragma unroll
  for (int k = 0; k < 128; k++) {
    float w = Wbase[k * 32];
    #pragma unroll
    for (int r = 0; r < ROWS; r++) acc[r] += hs[r][k] * w;
  }
  #pragma unroll
  for (int r = 0; r < ROWS; r++) {
    int gr = r0 + r;
    if (gr < n) PQ[(size_t)gr * 64 + c] = acc[r];
  }
}

// ---------------- edge: out[e] = P[src] + Q[dst] + ea[e]@Wc + b -------------
// 256 threads = 8 edges x 32 cols
__global__ void k_edge(const int* __restrict__ src, const int* __restrict__ dst,
                       const float* __restrict__ ea, const float* __restrict__ PQ,
                       const float* __restrict__ We, const float* __restrict__ be,
                       float* __restrict__ out, int ne) {
  __shared__ float eas[8][16];
  int le = threadIdx.x >> 5;
  int j = threadIdx.x & 31;
  int e = blockIdx.x * 8 + le;
  if (e < ne && j < 4)
    ((float4*)eas[le])[j] = ((const float4*)(ea + (size_t)e * 16))[j];
  __syncthreads();
  if (e >= ne) return;
  int s = src[e], d = dst[e];
  float acc = PQ[(size_t)s * 64 + j] + PQ[(size_t)d * 64 + 32 + j] + be[j];
  #pragma unroll
  for (int k = 0; k < 16; k++)
    acc += eas[le][k] * We[(256 + k) * 32 + j];
  out[(size_t)e * 32 + j] = acc;
}

extern "C" void kernel_launch(void* const* d_in, const int* in_sizes, int n_in,
                              void* d_out, int out_size, void* d_ws, size_t ws_size,
                              hipStream_t stream) {
  const float* x  = (const float*)d_in[0];
  const int*   ei = (const int*)d_in[1];
  const float* ea = (const float*)d_in[2];
  const float* W1 = (const float*)d_in[3];
  const float* b1 = (const float*)d_in[4];
  const float* W2 = (const float*)d_in[5];
  const float* b2 = (const float*)d_in[6];
  const float* We = (const float*)d_in[7];
  const float* be = (const float*)d_in[8];
  float* out = (float*)d_out;
  const int* src = ei;
  const int* dst = ei + NE;

  char* w = (char*)d_ws;
  auto alloc = [&](size_t b) {
    void* p = (void*)w;
    w += (b + 255) & ~(size_t)255;
    return p;
  };
  int* cnt   = (int*)alloc(NN * 4);
  int* cur   = (int*)alloc(NN * 4);
  int* offs  = (int*)alloc((NN + 1) * 4);
  int* bsum  = (int*)alloc(256 * 4);
  int* adj   = (int*)alloc((size_t)NE * 4);
  float* dinv = (float*)alloc(NN * 4);
  float* g   = (float*)alloc((size_t)NN * HID * 4);
  float* h   = (float*)alloc((size_t)NN * HID * 4);
  float* pq  = (float*)alloc((size_t)NN * 64 * 4);

  const int nblkN = (NN + 255) / 256;   // 196
  const int nblkE = (NE + 255) / 256;

  k_zero<<<nblkN, 256, 0, stream>>>(cnt, cur, NN);
  k_count<<<nblkE, 256, 0, stream>>>(dst, cnt, NE);
  k_scan1<<<nblkN, 256, 0, stream>>>(cnt, offs, bsum, NN);
  k_scan2<<<1, 256, 0, stream>>>(bsum, offs + NN, nblkN);
  k_scan3<<<nblkN, 256, 0, stream>>>(offs, bsum, NN);
  k_dinv<<<nblkN, 256, 0, stream>>>(cnt, dinv, NN);
  k_fill<<<nblkE, 256, 0, stream>>>(src, dst, offs, cur, adj, NE);

  k_gemm<64><<<(NN + 3) / 4, 128, 0, stream>>>(x, W1, dinv, g, NN);
  k_agg<<<(NN + 3) / 4, 256, 0, stream>>>(g, offs, adj, dinv, b1, h, NN);
  k_gemm<128><<<(NN + 3) / 4, 128, 0, stream>>>(h, W2, dinv, g, NN);
  k_agg<<<(NN + 3) / 4, 256, 0, stream>>>(g, offs, adj, dinv, b2, h, NN);
  k_pq<<<(NN + 7) / 8, 64, 0, stream>>>(h, We, pq, NN);
  k_edge<<<(NE + 7) / 8, 256, 0, stream>>>(src, dst, ea, pq, We, be, out, NE);
}

// Round 2
// 490.326 us; speedup vs baseline: 7.4729x; 7.4729x over previous
//
#include <hip/hip_runtime.h>

#define NN 50000
#define NE 800000
#define HID 128

// ---------------- CSR build ----------------
__global__ void k_zero(int* cnt, int* cur, int n) {
  int i = blockIdx.x * blockDim.x + threadIdx.x;
  if (i < n) { cnt[i] = 0; cur[i] = 0; }
}

__global__ void k_count(const int* dst, int* cnt, int e) {
  int i = blockIdx.x * blockDim.x + threadIdx.x;
  if (i < e) atomicAdd(&cnt[dst[i]], 1);
}

__global__ void k_scan1(const int* cnt, int* offs, int* bsum, int n) {
  __shared__ int s[256];
  int i = blockIdx.x * 256 + threadIdx.x;
  int v = (i < n) ? cnt[i] : 0;
  s[threadIdx.x] = v;
  __syncthreads();
  #pragma unroll
  for (int d = 1; d < 256; d <<= 1) {
    int t = (threadIdx.x >= d) ? s[threadIdx.x - d] : 0;
    __syncthreads();
    s[threadIdx.x] += t;
    __syncthreads();
  }
  if (i < n) offs[i] = s[threadIdx.x] - v;
  if (threadIdx.x == 255) bsum[blockIdx.x] = s[255];
}

__global__ void k_scan2(int* bsum, int* offsN, int nb) {
  __shared__ int s[256];
  int v = (threadIdx.x < nb) ? bsum[threadIdx.x] : 0;
  s[threadIdx.x] = v;
  __syncthreads();
  #pragma unroll
  for (int d = 1; d < 256; d <<= 1) {
    int t = (threadIdx.x >= d) ? s[threadIdx.x - d] : 0;
    __syncthreads();
    s[threadIdx.x] += t;
    __syncthreads();
  }
  if (threadIdx.x < nb) bsum[threadIdx.x] = s[threadIdx.x] - v;
  if (threadIdx.x == 255) *offsN = s[255];
}

__global__ void k_scan3(int* offs, const int* bsum, int n) {
  int i = blockIdx.x * blockDim.x + threadIdx.x;
  if (i < n) offs[i] += bsum[i >> 8];
}

__global__ void k_dinv(const int* cnt, float* dinv, int n) {
  int i = blockIdx.x * blockDim.x + threadIdx.x;
  if (i < n) dinv[i] = rsqrtf((float)(cnt[i] + 1));
}

__global__ void k_fill(const int* src, const int* dst, const int* offs,
                       int* cur, int* adj, int e) {
  int i = blockIdx.x * blockDim.x + threadIdx.x;
  if (i < e) {
    int d = dst[i];
    int pos = atomicAdd(&cur[d], 1);
    adj[offs[d] + pos] = src[i];
  }
}

// ---------------- node GEMM: out[r][c] = dinv[r] * sum_k X[r][k]*W[k][c] ----
// 256 threads, 32 rows/block, 16 rows per thread (rg = tid>>7), col = tid&127.
// W staged in LDS in 32-row chunks (never unrolled global loads -> no spills).
template <int K>
__global__ __launch_bounds__(256) void k_gemm2(const float* __restrict__ X,
                                               const float* __restrict__ W,
                                               const float* __restrict__ dinv,
                                               float* __restrict__ out, int n) {
  const int ROWS = 32;
  __shared__ float xs[ROWS][K];
  __shared__ float wl[32][128];
  int r0 = blockIdx.x * ROWS;
  int col = threadIdx.x & 127;
  int rg = threadIdx.x >> 7;  // 0..1
  // stage X tile (float4)
  const int X4 = ROWS * K / 4;
  for (int idx = threadIdx.x; idx < X4; idx += 256) {
    int r = idx / (K / 4), k4 = idx % (K / 4);
    int gr = r0 + r;
    float4 v = make_float4(0.f, 0.f, 0.f, 0.f);
    if (gr < n) v = ((const float4*)(X + (size_t)gr * K))[k4];
    ((float4*)xs[r])[k4] = v;
  }
  float acc[16];
  #pragma unroll
  for (int i = 0; i < 16; i++) acc[i] = 0.f;
  for (int kb = 0; kb < K; kb += 32) {
    __syncthreads();
    // stage W[kb..kb+32][0..128] = 1024 float4
    for (int idx = threadIdx.x; idx < 1024; idx += 256) {
      int k = idx >> 5, c4 = idx & 31;
      ((float4*)wl[k])[c4] = ((const float4*)(W + (size_t)(kb + k) * 128))[c4];
    }
    __syncthreads();
    #pragma unroll
    for (int kk = 0; kk < 32; kk += 4) {
      float w0 = wl[kk + 0][col];
      float w1 = wl[kk + 1][col];
      float w2 = wl[kk + 2][col];
      float w3 = wl[kk + 3][col];
      #pragma unroll
      for (int r = 0; r < 16; r++) {
        float4 xv = *(const float4*)&xs[rg * 16 + r][kb + kk];
        acc[r] += xv.x * w0 + xv.y * w1 + xv.z * w2 + xv.w * w3;
      }
    }
  }
  #pragma unroll
  for (int r = 0; r < 16; r++) {
    int gr = r0 + rg * 16 + r;
    if (gr < n) out[(size_t)gr * 128 + col] = acc[r] * dinv[gr];
  }
}

// ---------------- aggregation: h[v] = relu(dinv[v]*(g[v] + sum g[src]) + b) --
__global__ void k_agg(const float* __restrict__ g, const int* __restrict__ offs,
                      const int* __restrict__ adj, const float* __restrict__ dinv,
                      const float* __restrict__ bias, float* __restrict__ out,
                      int n) {
  int node = blockIdx.x * (blockDim.x >> 6) + (threadIdx.x >> 6);
  if (node >= n) return;
  int lane = threadIdx.x & 63;
  const float2* gp = (const float2*)(g + (size_t)node * 128);
  float2 acc = gp[lane];
  int s = offs[node], e = offs[node + 1];
  for (int i = s; i < e; i++) {
    int src = adj[i];
    float2 v = ((const float2*)(g + (size_t)src * 128))[lane];
    acc.x += v.x;
    acc.y += v.y;
  }
  float dv = dinv[node];
  float bx = bias[lane * 2], by = bias[lane * 2 + 1];
  float2 o;
  o.x = fmaxf(dv * acc.x + bx, 0.f);
  o.y = fmaxf(dv * acc.y + by, 0.f);
  ((float2*)(out + (size_t)node * 128))[lane] = o;
}

// ---------------- PQ: PQ[v][0:32] = h@Wa, PQ[v][32:64] = h@Wb ---------------
// 256 threads, 32 rows/block, 8 rows/thread (rg = tid>>6), col = tid&63.
// Fused W tile (Wa||Wb as [128][64]) staged in LDS.
__global__ __launch_bounds__(256) void k_pq2(const float* __restrict__ H,
                                             const float* __restrict__ We,
                                             float* __restrict__ PQ, int n) {
  const int ROWS = 32;
  __shared__ float hs[ROWS][128];
  __shared__ float wl[128][64];
  int r0 = blockIdx.x * ROWS;
  int col = threadIdx.x & 63;
  int rg = threadIdx.x >> 6;  // 0..3
  // stage H tile (1024 float4)
  for (int idx = threadIdx.x; idx < 1024; idx += 256) {
    int r = idx >> 5, k4 = idx & 31;
    int gr = r0 + r;
    float4 v = make_float4(0.f, 0.f, 0.f, 0.f);
    if (gr < n) v = ((const float4*)(H + (size_t)gr * 128))[k4];
    ((float4*)hs[r])[k4] = v;
  }
  // stage fused W: wl[k][c] = (c<32) ? We[k*32+c] : We[(128+k)*32+(c-32)]
  // 2048 float4
  for (int idx = threadIdx.x; idx < 2048; idx += 256) {
    int k = idx >> 4, c4 = idx & 15;
    int c = c4 * 4;
    float4 v;
    if (c < 32)
      v = *(const float4*)(We + (size_t)k * 32 + c);
    else
      v = *(const float4*)(We + (size_t)(128 + k) * 32 + (c - 32));
    ((float4*)wl[k])[c4] = v;
  }
  __syncthreads();
  float acc[8];
  #pragma unroll
  for (int i = 0; i < 8; i++) acc[i] = 0.f;
  #pragma unroll 4
  for (int kk = 0; kk < 128; kk += 4) {
    float w0 = wl[kk + 0][col];
    float w1 = wl[kk + 1][col];
    float w2 = wl[kk + 2][col];
    float w3 = wl[kk + 3][col];
    #pragma unroll
    for (int r = 0; r < 8; r++) {
      float4 xv = *(const float4*)&hs[rg * 8 + r][kk];
      acc[r] += xv.x * w0 + xv.y * w1 + xv.z * w2 + xv.w * w3;
    }
  }
  #pragma unroll
  for (int r = 0; r < 8; r++) {
    int gr = r0 + rg * 8 + r;
    if (gr < n) PQ[(size_t)gr * 64 + col] = acc[r];
  }
}

// ---------------- edge: out[e] = P[src] + Q[dst] + ea[e]@Wc + b -------------
__global__ __launch_bounds__(256) void k_edge2(const int* __restrict__ src,
                                               const int* __restrict__ dst,
                                               const float* __restrict__ ea,
                                               const float* __restrict__ PQ,
                                               const float* __restrict__ We,
                                               const float* __restrict__ be,
                                               float* __restrict__ out, int ne) {
  __shared__ float eas[8][16];
  __shared__ float wcs[16][32];
  __shared__ float bes[32];
  int le = threadIdx.x >> 5;
  int j = threadIdx.x & 31;
  int e = blockIdx.x * 8 + le;
  // stage Wc (rows 256..271 of We): 512 floats = 128 float4
  if (threadIdx.x < 128)
    ((float4*)wcs)[threadIdx.x] = ((const float4*)(We + 256 * 32))[threadIdx.x];
  if (threadIdx.x < 32) bes[threadIdx.x] = be[threadIdx.x];
  if (e < ne && j < 4)
    ((float4*)eas[le])[j] = ((const float4*)(ea + (size_t)e * 16))[j];
  __syncthreads();
  if (e >= ne) return;
  int s = src[e], d = dst[e];
  float acc = PQ[(size_t)s * 64 + j] + PQ[(size_t)d * 64 + 32 + j] + bes[j];
  #pragma unroll
  for (int k = 0; k < 16; k++)
    acc += eas[le][k] * wcs[k][j];
  out[(size_t)e * 32 + j] = acc;
}

extern "C" void kernel_launch(void* const* d_in, const int* in_sizes, int n_in,
                              void* d_out, int out_size, void* d_ws, size_t ws_size,
                              hipStream_t stream) {
  const float* x  = (const float*)d_in[0];
  const int*   ei = (const int*)d_in[1];
  const float* ea = (const float*)d_in[2];
  const float* W1 = (const float*)d_in[3];
  const float* b1 = (const float*)d_in[4];
  const float* W2 = (const float*)d_in[5];
  const float* b2 = (const float*)d_in[6];
  const float* We = (const float*)d_in[7];
  const float* be = (const float*)d_in[8];
  float* out = (float*)d_out;
  const int* src = ei;
  const int* dst = ei + NE;

  char* w = (char*)d_ws;
  auto alloc = [&](size_t b) {
    void* p = (void*)w;
    w += (b + 255) & ~(size_t)255;
    return p;
  };
  int* cnt   = (int*)alloc(NN * 4);
  int* cur   = (int*)alloc(NN * 4);
  int* offs  = (int*)alloc((NN + 1) * 4);
  int* bsum  = (int*)alloc(256 * 4);
  int* adj   = (int*)alloc((size_t)NE * 4);
  float* dinv = (float*)alloc(NN * 4);
  float* g   = (float*)alloc((size_t)NN * HID * 4);
  float* h   = (float*)alloc((size_t)NN * HID * 4);
  float* pq  = (float*)alloc((size_t)NN * 64 * 4);

  const int nblkN = (NN + 255) / 256;
  const int nblkE = (NE + 255) / 256;

  k_zero<<<nblkN, 256, 0, stream>>>(cnt, cur, NN);
  k_count<<<nblkE, 256, 0, stream>>>(dst, cnt, NE);
  k_scan1<<<nblkN, 256, 0, stream>>>(cnt, offs, bsum, NN);
  k_scan2<<<1, 256, 0, stream>>>(bsum, offs + NN, nblkN);
  k_scan3<<<nblkN, 256, 0, stream>>>(offs, bsum, NN);
  k_dinv<<<nblkN, 256, 0, stream>>>(cnt, dinv, NN);
  k_fill<<<nblkE, 256, 0, stream>>>(src, dst, offs, cur, adj, NE);

  const int gemmBlk = (NN + 31) / 32;  // 1563
  k_gemm2<64><<<gemmBlk, 256, 0, stream>>>(x, W1, dinv, g, NN);
  k_agg<<<(NN + 3) / 4, 256, 0, stream>>>(g, offs, adj, dinv, b1, h, NN);
  k_gemm2<128><<<gemmBlk, 256, 0, stream>>>(h, W2, dinv, g, NN);
  k_agg<<<(NN + 3) / 4, 256, 0, stream>>>(g, offs, adj, dinv, b2, h, NN);
  k_pq2<<<gemmBlk, 256, 0, stream>>>(h, We, pq, NN);
  k_edge2<<<(NE + 7) / 8, 256, 0, stream>>>(src, dst, ea, pq, We, be, out, NE);
}

// Round 3
// 403.882 us; speedup vs baseline: 9.0724x; 1.2140x over previous
//
#include <hip/hip_runtime.h>

#define NN 50000
#define NE 800000
#define HID 128

// ---------------- CSR build ----------------
__global__ void k_zero(int* cnt, int* cur, int n) {
  int i = blockIdx.x * blockDim.x + threadIdx.x;
  if (i < n) { cnt[i] = 0; cur[i] = 0; }
}

__global__ void k_count(const int* dst, int* cnt, int e) {
  int i = blockIdx.x * blockDim.x + threadIdx.x;
  if (i < e) atomicAdd(&cnt[dst[i]], 1);
}

__global__ void k_scan1(const int* cnt, int* offs, int* bsum, int n) {
  __shared__ int s[256];
  int i = blockIdx.x * 256 + threadIdx.x;
  int v = (i < n) ? cnt[i] : 0;
  s[threadIdx.x] = v;
  __syncthreads();
  #pragma unroll
  for (int d = 1; d < 256; d <<= 1) {
    int t = (threadIdx.x >= d) ? s[threadIdx.x - d] : 0;
    __syncthreads();
    s[threadIdx.x] += t;
    __syncthreads();
  }
  if (i < n) offs[i] = s[threadIdx.x] - v;
  if (threadIdx.x == 255) bsum[blockIdx.x] = s[255];
}

__global__ void k_scan2(int* bsum, int* offsN, int nb) {
  __shared__ int s[256];
  int v = (threadIdx.x < nb) ? bsum[threadIdx.x] : 0;
  s[threadIdx.x] = v;
  __syncthreads();
  #pragma unroll
  for (int d = 1; d < 256; d <<= 1) {
    int t = (threadIdx.x >= d) ? s[threadIdx.x - d] : 0;
    __syncthreads();
    s[threadIdx.x] += t;
    __syncthreads();
  }
  if (threadIdx.x < nb) bsum[threadIdx.x] = s[threadIdx.x] - v;
  if (threadIdx.x == 255) *offsN = s[255];
}

// fused: offs += block prefix; dinv = rsqrt(deg+1)
__global__ void k_scan3_dinv(int* offs, const int* bsum, const int* cnt,
                             float* dinv, int n) {
  int i = blockIdx.x * blockDim.x + threadIdx.x;
  if (i < n) {
    offs[i] += bsum[i >> 8];
    dinv[i] = rsqrtf((float)(cnt[i] + 1));
  }
}

__global__ void k_fill(const int* src, const int* dst, const int* offs,
                       int* cur, int* adj, int e) {
  int i = blockIdx.x * blockDim.x + threadIdx.x;
  if (i < e) {
    int d = dst[i];
    int pos = atomicAdd(&cur[d], 1);
    adj[offs[d] + pos] = src[i];
  }
}

// ---------------- node GEMM: out[r][c] = dinv[r] * sum_k X[r][k]*W[k][c] ----
template <int K>
__global__ __launch_bounds__(256) void k_gemm2(const float* __restrict__ X,
                                               const float* __restrict__ W,
                                               const float* __restrict__ dinv,
                                               float* __restrict__ out, int n) {
  const int ROWS = 32;
  __shared__ float xs[ROWS][K];
  __shared__ float wl[32][128];
  int r0 = blockIdx.x * ROWS;
  int col = threadIdx.x & 127;
  int rg = threadIdx.x >> 7;  // 0..1
  const int X4 = ROWS * K / 4;
  for (int idx = threadIdx.x; idx < X4; idx += 256) {
    int r = idx / (K / 4), k4 = idx % (K / 4);
    int gr = r0 + r;
    float4 v = make_float4(0.f, 0.f, 0.f, 0.f);
    if (gr < n) v = ((const float4*)(X + (size_t)gr * K))[k4];
    ((float4*)xs[r])[k4] = v;
  }
  float acc[16];
  #pragma unroll
  for (int i = 0; i < 16; i++) acc[i] = 0.f;
  for (int kb = 0; kb < K; kb += 32) {
    __syncthreads();
    for (int idx = threadIdx.x; idx < 1024; idx += 256) {
      int k = idx >> 5, c4 = idx & 31;
      ((float4*)wl[k])[c4] = ((const float4*)(W + (size_t)(kb + k) * 128))[c4];
    }
    __syncthreads();
    #pragma unroll
    for (int kk = 0; kk < 32; kk += 4) {
      float w0 = wl[kk + 0][col];
      float w1 = wl[kk + 1][col];
      float w2 = wl[kk + 2][col];
      float w3 = wl[kk + 3][col];
      #pragma unroll
      for (int r = 0; r < 16; r++) {
        float4 xv = *(const float4*)&xs[rg * 16 + r][kb + kk];
        acc[r] += xv.x * w0 + xv.y * w1 + xv.z * w2 + xv.w * w3;
      }
    }
  }
  #pragma unroll
  for (int r = 0; r < 16; r++) {
    int gr = r0 + rg * 16 + r;
    if (gr < n) out[(size_t)gr * 128 + col] = acc[r] * dinv[gr];
  }
}

// ---------------- aggregation: h[v] = relu(dinv[v]*(g[v] + sum g[src]) + b) --
// one wave per node, float2/lane; neighbor loop unrolled x4 (4 gathers in flight)
__global__ void k_agg(const float* __restrict__ g, const int* __restrict__ offs,
                      const int* __restrict__ adj, const float* __restrict__ dinv,
                      const float* __restrict__ bias, float* __restrict__ out,
                      int n) {
  int node = blockIdx.x * (blockDim.x >> 6) + (threadIdx.x >> 6);
  if (node >= n) return;
  int lane = threadIdx.x & 63;
  float2 a0 = ((const float2*)(g + (size_t)node * 128))[lane];
  float2 a1 = make_float2(0.f, 0.f);
  float2 a2 = make_float2(0.f, 0.f);
  float2 a3 = make_float2(0.f, 0.f);
  int s = offs[node], e = offs[node + 1];
  int i = s;
  for (; i + 4 <= e; i += 4) {
    int s0 = adj[i], s1 = adj[i + 1], s2 = adj[i + 2], s3 = adj[i + 3];
    float2 v0 = ((const float2*)(g + (size_t)s0 * 128))[lane];
    float2 v1 = ((const float2*)(g + (size_t)s1 * 128))[lane];
    float2 v2 = ((const float2*)(g + (size_t)s2 * 128))[lane];
    float2 v3 = ((const float2*)(g + (size_t)s3 * 128))[lane];
    a0.x += v0.x; a0.y += v0.y;
    a1.x += v1.x; a1.y += v1.y;
    a2.x += v2.x; a2.y += v2.y;
    a3.x += v3.x; a3.y += v3.y;
  }
  for (; i < e; i++) {
    int s0 = adj[i];
    float2 v0 = ((const float2*)(g + (size_t)s0 * 128))[lane];
    a0.x += v0.x; a0.y += v0.y;
  }
  float2 acc;
  acc.x = (a0.x + a1.x) + (a2.x + a3.x);
  acc.y = (a0.y + a1.y) + (a2.y + a3.y);
  float dv = dinv[node];
  float bx = bias[lane * 2], by = bias[lane * 2 + 1];
  float2 o;
  o.x = fmaxf(dv * acc.x + bx, 0.f);
  o.y = fmaxf(dv * acc.y + by, 0.f);
  ((float2*)(out + (size_t)node * 128))[lane] = o;
}

// ---------------- PQ: PQ[v][0:32] = h@Wa, PQ[v][32:64] = h@Wb ---------------
__global__ __launch_bounds__(256) void k_pq2(const float* __restrict__ H,
                                             const float* __restrict__ We,
                                             float* __restrict__ PQ, int n) {
  const int ROWS = 32;
  __shared__ float hs[ROWS][128];
  __shared__ float wl[128][64];
  int r0 = blockIdx.x * ROWS;
  int col = threadIdx.x & 63;
  int rg = threadIdx.x >> 6;  // 0..3
  for (int idx = threadIdx.x; idx < 1024; idx += 256) {
    int r = idx >> 5, k4 = idx & 31;
    int gr = r0 + r;
    float4 v = make_float4(0.f, 0.f, 0.f, 0.f);
    if (gr < n) v = ((const float4*)(H + (size_t)gr * 128))[k4];
    ((float4*)hs[r])[k4] = v;
  }
  for (int idx = threadIdx.x; idx < 2048; idx += 256) {
    int k = idx >> 4, c4 = idx & 15;
    int c = c4 * 4;
    float4 v;
    if (c < 32)
      v = *(const float4*)(We + (size_t)k * 32 + c);
    else
      v = *(const float4*)(We + (size_t)(128 + k) * 32 + (c - 32));
    ((float4*)wl[k])[c4] = v;
  }
  __syncthreads();
  float acc[8];
  #pragma unroll
  for (int i = 0; i < 8; i++) acc[i] = 0.f;
  #pragma unroll 4
  for (int kk = 0; kk < 128; kk += 4) {
    float w0 = wl[kk + 0][col];
    float w1 = wl[kk + 1][col];
    float w2 = wl[kk + 2][col];
    float w3 = wl[kk + 3][col];
    #pragma unroll
    for (int r = 0; r < 8; r++) {
      float4 xv = *(const float4*)&hs[rg * 8 + r][kk];
      acc[r] += xv.x * w0 + xv.y * w1 + xv.z * w2 + xv.w * w3;
    }
  }
  #pragma unroll
  for (int r = 0; r < 8; r++) {
    int gr = r0 + rg * 8 + r;
    if (gr < n) PQ[(size_t)gr * 64 + col] = acc[r];
  }
}

// ---------------- edge: out[e] = P[src] + Q[dst] + ea[e]@Wc + b -------------
// 32 edges/block; each thread: 4 edges x 1 col -> 8 independent PQ gathers in
// flight before any use (latency hiding).
__global__ __launch_bounds__(256) void k_edge3(const int* __restrict__ src,
                                               const int* __restrict__ dst,
                                               const float* __restrict__ ea,
                                               const float* __restrict__ PQ,
                                               const float* __restrict__ We,
                                               const float* __restrict__ be,
                                               float* __restrict__ out, int ne) {
  __shared__ float eas[32][16];
  __shared__ float wcs[16][32];
  __shared__ float bes[32];
  int j = threadIdx.x & 31;
  int g8 = threadIdx.x >> 5;  // 0..7
  int ebase = blockIdx.x * 32;
  if (threadIdx.x < 128)
    ((float4*)wcs)[threadIdx.x] = ((const float4*)(We + 256 * 32))[threadIdx.x];
  if (threadIdx.x < 32) bes[threadIdx.x] = be[threadIdx.x];
  if (threadIdx.x < 128) {
    int le = threadIdx.x >> 2, q = threadIdx.x & 3;
    int e = ebase + le;
    float4 v = make_float4(0.f, 0.f, 0.f, 0.f);
    if (e < ne) v = ((const float4*)(ea + (size_t)e * 16))[q];
    ((float4*)eas[le])[q] = v;
  }
  // issue all 8 index loads, then all 8 gathers (independent)
  int e0 = ebase + g8;
  float pv[4], qv[4];
  #pragma unroll
  for (int u = 0; u < 4; u++) {
    int e = e0 + u * 8;
    bool ok = e < ne;
    int s = ok ? src[e] : 0;
    int d = ok ? dst[e] : 0;
    pv[u] = ok ? PQ[(size_t)s * 64 + j] : 0.f;
    qv[u] = ok ? PQ[(size_t)d * 64 + 32 + j] : 0.f;
  }
  __syncthreads();
  #pragma unroll
  for (int u = 0; u < 4; u++) {
    int e = e0 + u * 8;
    if (e >= ne) continue;
    int lrow = g8 + u * 8;
    float acc = pv[u] + qv[u] + bes[j];
    #pragma unroll
    for (int k = 0; k < 16; k++)
      acc += eas[lrow][k] * wcs[k][j];
    out[(size_t)e * 32 + j] = acc;
  }
}

extern "C" void kernel_launch(void* const* d_in, const int* in_sizes, int n_in,
                              void* d_out, int out_size, void* d_ws, size_t ws_size,
                              hipStream_t stream) {
  const float* x  = (const float*)d_in[0];
  const int*   ei = (const int*)d_in[1];
  const float* ea = (const float*)d_in[2];
  const float* W1 = (const float*)d_in[3];
  const float* b1 = (const float*)d_in[4];
  const float* W2 = (const float*)d_in[5];
  const float* b2 = (const float*)d_in[6];
  const float* We = (const float*)d_in[7];
  const float* be = (const float*)d_in[8];
  float* out = (float*)d_out;
  const int* src = ei;
  const int* dst = ei + NE;

  char* w = (char*)d_ws;
  auto alloc = [&](size_t b) {
    void* p = (void*)w;
    w += (b + 255) & ~(size_t)255;
    return p;
  };
  int* cnt   = (int*)alloc(NN * 4);
  int* cur   = (int*)alloc(NN * 4);
  int* offs  = (int*)alloc((NN + 1) * 4);
  int* bsum  = (int*)alloc(256 * 4);
  int* adj   = (int*)alloc((size_t)NE * 4);
  float* dinv = (float*)alloc(NN * 4);
  float* g   = (float*)alloc((size_t)NN * HID * 4);
  float* h   = (float*)alloc((size_t)NN * HID * 4);
  float* pq  = (float*)alloc((size_t)NN * 64 * 4);

  const int nblkN = (NN + 255) / 256;
  const int nblkE = (NE + 255) / 256;

  k_zero<<<nblkN, 256, 0, stream>>>(cnt, cur, NN);
  k_count<<<nblkE, 256, 0, stream>>>(dst, cnt, NE);
  k_scan1<<<nblkN, 256, 0, stream>>>(cnt, offs, bsum, NN);
  k_scan2<<<1, 256, 0, stream>>>(bsum, offs + NN, nblkN);
  k_scan3_dinv<<<nblkN, 256, 0, stream>>>(offs, bsum, cnt, dinv, NN);
  k_fill<<<nblkE, 256, 0, stream>>>(src, dst, offs, cur, adj, NE);

  const int gemmBlk = (NN + 31) / 32;  // 1563
  k_gemm2<64><<<gemmBlk, 256, 0, stream>>>(x, W1, dinv, g, NN);
  k_agg<<<(NN + 3) / 4, 256, 0, stream>>>(g, offs, adj, dinv, b1, h, NN);
  k_gemm2<128><<<gemmBlk, 256, 0, stream>>>(h, W2, dinv, g, NN);
  k_agg<<<(NN + 3) / 4, 256, 0, stream>>>(g, offs, adj, dinv, b2, h, NN);
  k_pq2<<<gemmBlk, 256, 0, stream>>>(h, We, pq, NN);
  k_edge3<<<(NE + 31) / 32, 256, 0, stream>>>(src, dst, ea, pq, We, be, out, NE);
}

// Round 5
// 377.123 us; speedup vs baseline: 9.7161x; 1.0710x over previous
//
#include <hip/hip_runtime.h>

#define NN 50000
#define NE 800000
#define HID 128

// ---------------- CSR build ----------------
__global__ void k_zero(int* cnt, int* cur, int n) {
  int i = blockIdx.x * blockDim.x + threadIdx.x;
  if (i < n) { cnt[i] = 0; cur[i] = 0; }
}

__global__ void k_count(const int* dst, int* cnt, int e) {
  int i = blockIdx.x * blockDim.x + threadIdx.x;
  if (i < e) atomicAdd(&cnt[dst[i]], 1);
}

__global__ void k_scan1(const int* cnt, int* offs, int* bsum, int n) {
  __shared__ int s[256];
  int i = blockIdx.x * 256 + threadIdx.x;
  int v = (i < n) ? cnt[i] : 0;
  s[threadIdx.x] = v;
  __syncthreads();
  #pragma unroll
  for (int d = 1; d < 256; d <<= 1) {
    int t = (threadIdx.x >= d) ? s[threadIdx.x - d] : 0;
    __syncthreads();
    s[threadIdx.x] += t;
    __syncthreads();
  }
  if (i < n) offs[i] = s[threadIdx.x] - v;
  if (threadIdx.x == 255) bsum[blockIdx.x] = s[255];
}

__global__ void k_scan2(int* bsum, int* offsN, int nb) {
  __shared__ int s[256];
  int v = (threadIdx.x < nb) ? bsum[threadIdx.x] : 0;
  s[threadIdx.x] = v;
  __syncthreads();
  #pragma unroll
  for (int d = 1; d < 256; d <<= 1) {
    int t = (threadIdx.x >= d) ? s[threadIdx.x - d] : 0;
    __syncthreads();
    s[threadIdx.x] += t;
    __syncthreads();
  }
  if (threadIdx.x < nb) bsum[threadIdx.x] = s[threadIdx.x] - v;
  if (threadIdx.x == 255) *offsN = s[255];
}

__global__ void k_scan3_dinv(int* offs, const int* bsum, const int* cnt,
                             float* dinv, int n) {
  int i = blockIdx.x * blockDim.x + threadIdx.x;
  if (i < n) {
    offs[i] += bsum[i >> 8];
    dinv[i] = rsqrtf((float)(cnt[i] + 1));
  }
}

__global__ void k_fill(const int* src, const int* dst, const int* offs,
                       int* cur, int* adj, int e) {
  int i = blockIdx.x * blockDim.x + threadIdx.x;
  if (i < e) {
    int d = dst[i];
    int pos = atomicAdd(&cur[d], 1);
    adj[offs[d] + pos] = src[i];
  }
}

// ---------------- node GEMM: out[r][c] = dinv[r] * sum_k X[r][k]*W[k][c] ----
template <int K>
__global__ __launch_bounds__(256) void k_gemm2(const float* __restrict__ X,
                                               const float* __restrict__ W,
                                               const float* __restrict__ dinv,
                                               float* __restrict__ out, int n) {
  const int ROWS = 32;
  __shared__ float xs[ROWS][K];
  __shared__ float wl[32][128];
  int r0 = blockIdx.x * ROWS;
  int col = threadIdx.x & 127;
  int rg = threadIdx.x >> 7;  // 0..1
  const int X4 = ROWS * K / 4;
  for (int idx = threadIdx.x; idx < X4; idx += 256) {
    int r = idx / (K / 4), k4 = idx % (K / 4);
    int gr = r0 + r;
    float4 v = make_float4(0.f, 0.f, 0.f, 0.f);
    if (gr < n) v = ((const float4*)(X + (size_t)gr * K))[k4];
    ((float4*)xs[r])[k4] = v;
  }
  float acc[16];
  #pragma unroll
  for (int i = 0; i < 16; i++) acc[i] = 0.f;
  for (int kb = 0; kb < K; kb += 32) {
    __syncthreads();
    for (int idx = threadIdx.x; idx < 1024; idx += 256) {
      int k = idx >> 5, c4 = idx & 31;
      ((float4*)wl[k])[c4] = ((const float4*)(W + (size_t)(kb + k) * 128))[c4];
    }
    __syncthreads();
    #pragma unroll
    for (int kk = 0; kk < 32; kk += 4) {
      float w0 = wl[kk + 0][col];
      float w1 = wl[kk + 1][col];
      float w2 = wl[kk + 2][col];
      float w3 = wl[kk + 3][col];
      #pragma unroll
      for (int r = 0; r < 16; r++) {
        float4 xv = *(const float4*)&xs[rg * 16 + r][kb + kk];
        acc[r] += xv.x * w0 + xv.y * w1 + xv.z * w2 + xv.w * w3;
      }
    }
  }
  #pragma unroll
  for (int r = 0; r < 16; r++) {
    int gr = r0 + rg * 16 + r;
    if (gr < n) out[(size_t)gr * 128 + col] = acc[r] * dinv[gr];
  }
}

// ---------------- aggregation: h[v] = relu(dinv[v]*(g[v] + sum g[src]) + b) --
// one wave per node; neighbor loop unrolled x8 (8 idx loads, then 8 gathers)
__global__ void k_agg(const float* __restrict__ g, const int* __restrict__ offs,
                      const int* __restrict__ adj, const float* __restrict__ dinv,
                      const float* __restrict__ bias, float* __restrict__ out,
                      int n) {
  int node = blockIdx.x * (blockDim.x >> 6) + (threadIdx.x >> 6);
  if (node >= n) return;
  int lane = threadIdx.x & 63;
  float2 a[8];
  a[0] = ((const float2*)(g + (size_t)node * 128))[lane];
  #pragma unroll
  for (int u = 1; u < 8; u++) a[u] = make_float2(0.f, 0.f);
  int s = offs[node], e = offs[node + 1];
  int i = s;
  for (; i + 8 <= e; i += 8) {
    int idx[8];
    #pragma unroll
    for (int u = 0; u < 8; u++) idx[u] = adj[i + u];
    #pragma unroll
    for (int u = 0; u < 8; u++) {
      float2 v = ((const float2*)(g + (size_t)idx[u] * 128))[lane];
      a[u].x += v.x; a[u].y += v.y;
    }
  }
  for (; i < e; i++) {
    float2 v = ((const float2*)(g + (size_t)adj[i] * 128))[lane];
    a[0].x += v.x; a[0].y += v.y;
  }
  float2 acc;
  acc.x = ((a[0].x + a[1].x) + (a[2].x + a[3].x)) +
          ((a[4].x + a[5].x) + (a[6].x + a[7].x));
  acc.y = ((a[0].y + a[1].y) + (a[2].y + a[3].y)) +
          ((a[4].y + a[5].y) + (a[6].y + a[7].y));
  float dv = dinv[node];
  float bx = bias[lane * 2], by = bias[lane * 2 + 1];
  float2 o;
  o.x = fmaxf(dv * acc.x + bx, 0.f);
  o.y = fmaxf(dv * acc.y + by, 0.f);
  ((float2*)(out + (size_t)node * 128))[lane] = o;
}

// ---------------- PQ: PQ[v][0:32] = h@Wa, PQ[v][32:64] = h@Wb ---------------
__global__ __launch_bounds__(256) void k_pq2(const float* __restrict__ H,
                                             const float* __restrict__ We,
                                             float* __restrict__ PQ, int n) {
  const int ROWS = 32;
  __shared__ float hs[ROWS][128];
  __shared__ float wl[128][64];
  int r0 = blockIdx.x * ROWS;
  int col = threadIdx.x & 63;
  int rg = threadIdx.x >> 6;  // 0..3
  for (int idx = threadIdx.x; idx < 1024; idx += 256) {
    int r = idx >> 5, k4 = idx & 31;
    int gr = r0 + r;
    float4 v = make_float4(0.f, 0.f, 0.f, 0.f);
    if (gr < n) v = ((const float4*)(H + (size_t)gr * 128))[k4];
    ((float4*)hs[r])[k4] = v;
  }
  for (int idx = threadIdx.x; idx < 2048; idx += 256) {
    int k = idx >> 4, c4 = idx & 15;
    int c = c4 * 4;
    float4 v;
    if (c < 32)
      v = *(const float4*)(We + (size_t)k * 32 + c);
    else
      v = *(const float4*)(We + (size_t)(128 + k) * 32 + (c - 32));
    ((float4*)wl[k])[c4] = v;
  }
  __syncthreads();
  float acc[8];
  #pragma unroll
  for (int i = 0; i < 8; i++) acc[i] = 0.f;
  #pragma unroll 4
  for (int kk = 0; kk < 128; kk += 4) {
    float w0 = wl[kk + 0][col];
    float w1 = wl[kk + 1][col];
    float w2 = wl[kk + 2][col];
    float w3 = wl[kk + 3][col];
    #pragma unroll
    for (int r = 0; r < 8; r++) {
      float4 xv = *(const float4*)&hs[rg * 8 + r][kk];
      acc[r] += xv.x * w0 + xv.y * w1 + xv.z * w2 + xv.w * w3;
    }
  }
  #pragma unroll
  for (int r = 0; r < 8; r++) {
    int gr = r0 + rg * 8 + r;
    if (gr < n) PQ[(size_t)gr * 64 + col] = acc[r];
  }
}

// ---------------- edge: out[e] = P[src] + Q[dst] + ea[e]@Wc + b -------------
// 64 edges/block; idx staged in LDS (coalesced), each thread owns 8 edges x 1
// col -> 16 independent PQ gathers in flight.
__global__ __launch_bounds__(256) void k_edge4(const int* __restrict__ src,
                                               const int* __restrict__ dst,
                                               const float* __restrict__ ea,
                                               const float* __restrict__ PQ,
                                               const float* __restrict__ We,
                                               const float* __restrict__ be,
                                               float* __restrict__ out, int ne) {
  __shared__ int sidx[64];
  __shared__ int didx[64];
  __shared__ float eas[64][16];
  __shared__ float wcs[16][32];
  __shared__ float bes[32];
  int tid = threadIdx.x;
  int ebase = blockIdx.x * 64;  // NE % 64 == 0
  // stage Wc + bias
  if (tid < 128)
    ((float4*)wcs)[tid] = ((const float4*)(We + 256 * 32))[tid];
  if (tid < 32) bes[tid] = be[tid];
  // stage indices (coalesced 64-wide)
  if (tid >= 128 && tid < 192) sidx[tid - 128] = src[ebase + tid - 128];
  if (tid >= 192)              didx[tid - 192] = dst[ebase + tid - 192];
  // stage ea: 64 edges x 16 f = 256 float4, one per thread
  {
    int row = tid >> 2, q = tid & 3;
    ((float4*)eas[row])[q] = ((const float4*)(ea + (size_t)(ebase + row) * 16))[q];
  }
  __syncthreads();
  int j = tid & 31;
  int grp = tid >> 5;  // 0..7
  // issue all 16 gathers before any use
  float pv[8], qv[8];
  int el[8];
  #pragma unroll
  for (int u = 0; u < 8; u++) el[u] = u * 8 + grp;
  #pragma unroll
  for (int u = 0; u < 8; u++) {
    int s = sidx[el[u]];
    int d = didx[el[u]];
    pv[u] = PQ[(size_t)s * 64 + j];
    qv[u] = PQ[(size_t)d * 64 + 32 + j];
  }
  #pragma unroll
  for (int u = 0; u < 8; u++) {
    int e = ebase + el[u];
    float acc = pv[u] + qv[u] + bes[j];
    #pragma unroll
    for (int k = 0; k < 16; k++)
      acc += eas[el[u]][k] * wcs[k][j];
    out[(size_t)e * 32 + j] = acc;
  }
}

extern "C" void kernel_launch(void* const* d_in, const int* in_sizes, int n_in,
                              void* d_out, int out_size, void* d_ws, size_t ws_size,
                              hipStream_t stream) {
  const float* x  = (const float*)d_in[0];
  const int*   ei = (const int*)d_in[1];
  const float* ea = (const float*)d_in[2];
  const float* W1 = (const float*)d_in[3];
  const float* b1 = (const float*)d_in[4];
  const float* W2 = (const float*)d_in[5];
  const float* b2 = (const float*)d_in[6];
  const float* We = (const float*)d_in[7];
  const float* be = (const float*)d_in[8];
  float* out = (float*)d_out;
  const int* src = ei;
  const int* dst = ei + NE;

  char* w = (char*)d_ws;
  auto alloc = [&](size_t b) {
    void* p = (void*)w;
    w += (b + 255) & ~(size_t)255;
    return p;
  };
  int* cnt   = (int*)alloc(NN * 4);
  int* cur   = (int*)alloc(NN * 4);
  int* offs  = (int*)alloc((NN + 1) * 4);
  int* bsum  = (int*)alloc(256 * 4);
  int* adj   = (int*)alloc((size_t)NE * 4);
  float* dinv = (float*)alloc(NN * 4);
  float* g   = (float*)alloc((size_t)NN * HID * 4);
  float* h   = (float*)alloc((size_t)NN * HID * 4);
  float* pq  = (float*)alloc((size_t)NN * 64 * 4);

  const int nblkN = (NN + 255) / 256;
  const int nblkE = (NE + 255) / 256;

  k_zero<<<nblkN, 256, 0, stream>>>(cnt, cur, NN);
  k_count<<<nblkE, 256, 0, stream>>>(dst, cnt, NE);
  k_scan1<<<nblkN, 256, 0, stream>>>(cnt, offs, bsum, NN);
  k_scan2<<<1, 256, 0, stream>>>(bsum, offs + NN, nblkN);
  k_scan3_dinv<<<nblkN, 256, 0, stream>>>(offs, bsum, cnt, dinv, NN);
  k_fill<<<nblkE, 256, 0, stream>>>(src, dst, offs, cur, adj, NE);

  const int gemmBlk = (NN + 31) / 32;  // 1563
  k_gemm2<64><<<gemmBlk, 256, 0, stream>>>(x, W1, dinv, g, NN);
  k_agg<<<(NN + 3) / 4, 256, 0, stream>>>(g, offs, adj, dinv, b1, h, NN);
  k_gemm2<128><<<gemmBlk, 256, 0, stream>>>(h, W2, dinv, g, NN);
  k_agg<<<(NN + 3) / 4, 256, 0, stream>>>(g, offs, adj, dinv, b2, h, NN);
  k_pq2<<<gemmBlk, 256, 0, stream>>>(h, We, pq, NN);
  k_edge4<<<NE / 64, 256, 0, stream>>>(src, dst, ea, pq, We, be, out, NE);
}

// Round 7
// 335.164 us; speedup vs baseline: 10.9325x; 1.1252x over previous
//
#include <hip/hip_runtime.h>

#define NN 50000
#define NE 800000

// ---------------- bf16 helpers ----------------
__device__ __forceinline__ float bf_lo(unsigned u) { return __uint_as_float(u << 16); }
__device__ __forceinline__ float bf_hi(unsigned u) { return __uint_as_float(u & 0xffff0000u); }
__device__ __forceinline__ unsigned pack_bf2(float a, float b) {
  unsigned ua = __float_as_uint(a);
  ua = (ua + 0x7fffu + ((ua >> 16) & 1u)) >> 16;
  unsigned ub = __float_as_uint(b);
  ub = (ub + 0x7fffu + ((ub >> 16) & 1u)) & 0xffff0000u;
  return ua | ub;
}

// ---------------- CSR build ----------------
__global__ void k_zero(int* cnt, int* cur, int n) {
  int i = blockIdx.x * blockDim.x + threadIdx.x;
  if (i < n) { cnt[i] = 0; cur[i] = 0; }
}

__global__ void k_count(const int* dst, int* cnt, int e) {
  int i = blockIdx.x * blockDim.x + threadIdx.x;
  if (i < e) atomicAdd(&cnt[dst[i]], 1);
}

__global__ void k_scan1(const int* cnt, int* offs, int* bsum, int n) {
  __shared__ int s[256];
  int i = blockIdx.x * 256 + threadIdx.x;
  int v = (i < n) ? cnt[i] : 0;
  s[threadIdx.x] = v;
  __syncthreads();
  #pragma unroll
  for (int d = 1; d < 256; d <<= 1) {
    int t = (threadIdx.x >= d) ? s[threadIdx.x - d] : 0;
    __syncthreads();
    s[threadIdx.x] += t;
    __syncthreads();
  }
  if (i < n) offs[i] = s[threadIdx.x] - v;
  if (threadIdx.x == 255) bsum[blockIdx.x] = s[255];
}

__global__ void k_scan2(int* bsum, int* offsN, int nb) {
  __shared__ int s[256];
  int v = (threadIdx.x < nb) ? bsum[threadIdx.x] : 0;
  s[threadIdx.x] = v;
  __syncthreads();
  #pragma unroll
  for (int d = 1; d < 256; d <<= 1) {
    int t = (threadIdx.x >= d) ? s[threadIdx.x - d] : 0;
    __syncthreads();
    s[threadIdx.x] += t;
    __syncthreads();
  }
  if (threadIdx.x < nb) bsum[threadIdx.x] = s[threadIdx.x] - v;
  if (threadIdx.x == 255) *offsN = s[255];
}

__global__ void k_scan3_dinv(int* offs, const int* bsum, const int* cnt,
                             float* dinv, int n) {
  int i = blockIdx.x * blockDim.x + threadIdx.x;
  if (i < n) {
    offs[i] += bsum[i >> 8];
    dinv[i] = rsqrtf((float)(cnt[i] + 1));
  }
}

__global__ void k_fill(const int* src, const int* dst, const int* offs,
                       int* cur, int* adj, int e) {
  int i = blockIdx.x * blockDim.x + threadIdx.x;
  if (i < e) {
    int d = dst[i];
    int pos = atomicAdd(&cur[d], 1);
    adj[offs[d] + pos] = src[i];
  }
}

// ---------------- prescale: xs[v] = bf16(dinv[v] * x[v]) (64 dims) ----------
__global__ void k_prescale(const float* __restrict__ x,
                           const float* __restrict__ dinv,
                           unsigned* __restrict__ xs, int n) {
  int i = blockIdx.x * blockDim.x + threadIdx.x;  // over n*32
  if (i >= n * 32) return;
  int v = i >> 5, c2 = i & 31;
  float d = dinv[v];
  float2 xv = ((const float2*)(x + (size_t)v * 64))[c2];
  xs[(size_t)v * 32 + c2] = pack_bf2(xv.x * d, xv.y * d);
}

// ---------------- agg64: z[v][0:64] = dinv[v]*(xs[v] + sum xs[src]) ---------
// half-wave (32 lanes) per node; 8 nodes per 256-block; bf16 rows (128 B)
__global__ void k_agg64(const unsigned* __restrict__ xs,
                        const int* __restrict__ offs, const int* __restrict__ adj,
                        const float* __restrict__ dinv, float* __restrict__ z,
                        int n) {
  int node = blockIdx.x * 8 + (threadIdx.x >> 5);
  if (node >= n) return;
  int lane = threadIdx.x & 31;
  float ax[8], ay[8];
  {
    unsigned u = xs[(size_t)node * 32 + lane];
    ax[0] = bf_lo(u); ay[0] = bf_hi(u);
  }
  #pragma unroll
  for (int u = 1; u < 8; u++) { ax[u] = 0.f; ay[u] = 0.f; }
  int s = offs[node], e = offs[node + 1];
  int i = s;
  for (; i + 8 <= e; i += 8) {
    int idx[8];
    #pragma unroll
    for (int u = 0; u < 8; u++) idx[u] = adj[i + u];
    #pragma unroll
    for (int u = 0; u < 8; u++) {
      unsigned uv = xs[(size_t)idx[u] * 32 + lane];
      ax[u] += bf_lo(uv); ay[u] += bf_hi(uv);
    }
  }
  for (; i < e; i++) {
    unsigned uv = xs[(size_t)adj[i] * 32 + lane];
    ax[0] += bf_lo(uv); ay[0] += bf_hi(uv);
  }
  float sx = ((ax[0] + ax[1]) + (ax[2] + ax[3])) + ((ax[4] + ax[5]) + (ax[6] + ax[7]));
  float sy = ((ay[0] + ay[1]) + (ay[2] + ay[3])) + ((ay[4] + ay[5]) + (ay[6] + ay[7]));
  float d = dinv[node];
  ((float2*)(z + (size_t)node * 64))[lane] = make_float2(sx * d, sy * d);
}

// ---------------- agg128: z[v][0:128] = dinv[v]*(hs[v] + sum hs[src]) -------
// full wave per node; 4 nodes per 256-block; bf16 rows (256 B)
__global__ void k_agg128(const unsigned* __restrict__ hs,
                         const int* __restrict__ offs, const int* __restrict__ adj,
                         const float* __restrict__ dinv, float* __restrict__ z,
                         int n) {
  int node = blockIdx.x * 4 + (threadIdx.x >> 6);
  if (node >= n) return;
  int lane = threadIdx.x & 63;
  float ax[8], ay[8];
  {
    unsigned u = hs[(size_t)node * 64 + lane];
    ax[0] = bf_lo(u); ay[0] = bf_hi(u);
  }
  #pragma unroll
  for (int u = 1; u < 8; u++) { ax[u] = 0.f; ay[u] = 0.f; }
  int s = offs[node], e = offs[node + 1];
  int i = s;
  for (; i + 8 <= e; i += 8) {
    int idx[8];
    #pragma unroll
    for (int u = 0; u < 8; u++) idx[u] = adj[i + u];
    #pragma unroll
    for (int u = 0; u < 8; u++) {
      unsigned uv = hs[(size_t)idx[u] * 64 + lane];
      ax[u] += bf_lo(uv); ay[u] += bf_hi(uv);
    }
  }
  for (; i < e; i++) {
    unsigned uv = hs[(size_t)adj[i] * 64 + lane];
    ax[0] += bf_lo(uv); ay[0] += bf_hi(uv);
  }
  float sx = ((ax[0] + ax[1]) + (ax[2] + ax[3])) + ((ax[4] + ax[5]) + (ax[6] + ax[7]));
  float sy = ((ay[0] + ay[1]) + (ay[2] + ay[3])) + ((ay[4] + ay[5]) + (ay[6] + ay[7]));
  float d = dinv[node];
  ((float2*)(z + (size_t)node * 128))[lane] = make_float2(sx * d, sy * d);
}

// ---------------- GEMM (no LDS, cache-broadcast): out = relu(Z@W + b) -------
// 32 rows x 128 cols per block; thread = 4 rows x 4 cols.
// EPI 0: store bf16, scaled by dinv[row] (for next-layer gather)
// EPI 1: store f32
template <int K, int EPI>
__global__ __launch_bounds__(256) void k_gemm3(const float* __restrict__ X,
                                               const float* __restrict__ W,
                                               const float* __restrict__ bias,
                                               const float* __restrict__ dinv,
                                               float* __restrict__ outf,
                                               unsigned* __restrict__ outb,
                                               int n) {
  int r0 = blockIdx.x * 32;
  int c0 = (threadIdx.x & 31) * 4;
  int rg = threadIdx.x >> 5;  // 0..7
  const float* xr[4];
  #pragma unroll
  for (int u = 0; u < 4; u++) {
    int rr = r0 + rg * 4 + u;
    if (rr > n - 1) rr = n - 1;
    xr[u] = X + (size_t)rr * K;
  }
  float acc[4][4];
  #pragma unroll
  for (int u = 0; u < 4; u++)
    #pragma unroll
    for (int c = 0; c < 4; c++) acc[u][c] = 0.f;
  #pragma unroll 2
  for (int k = 0; k < K; k += 4) {
    float4 w0 = *(const float4*)(W + (size_t)(k + 0) * 128 + c0);
    float4 w1 = *(const float4*)(W + (size_t)(k + 1) * 128 + c0);
    float4 w2 = *(const float4*)(W + (size_t)(k + 2) * 128 + c0);
    float4 w3 = *(const float4*)(W + (size_t)(k + 3) * 128 + c0);
    #pragma unroll
    for (int u = 0; u < 4; u++) {
      float4 xv = *(const float4*)(xr[u] + k);
      acc[u][0] += xv.x * w0.x + xv.y * w1.x + xv.z * w2.x + xv.w * w3.x;
      acc[u][1] += xv.x * w0.y + xv.y * w1.y + xv.z * w2.y + xv.w * w3.y;
      acc[u][2] += xv.x * w0.z + xv.y * w1.z + xv.z * w2.z + xv.w * w3.z;
      acc[u][3] += xv.x * w0.w + xv.y * w1.w + xv.z * w2.w + xv.w * w3.w;
    }
  }
  float4 bv = *(const float4*)(bias + c0);
  #pragma unroll
  for (int u = 0; u < 4; u++) {
    int row = r0 + rg * 4 + u;
    if (row >= n) break;
    float v0 = fmaxf(acc[u][0] + bv.x, 0.f);
    float v1 = fmaxf(acc[u][1] + bv.y, 0.f);
    float v2 = fmaxf(acc[u][2] + bv.z, 0.f);
    float v3 = fmaxf(acc[u][3] + bv.w, 0.f);
    if (EPI == 0) {
      float d = dinv[row];
      uint2 p;
      p.x = pack_bf2(v0 * d, v1 * d);
      p.y = pack_bf2(v2 * d, v3 * d);
      *(uint2*)(outb + (size_t)row * 64 + (c0 >> 1)) = p;
    } else {
      *(float4*)(outf + (size_t)row * 128 + c0) = make_float4(v0, v1, v2, v3);
    }
  }
}

// ---------------- PQ: PQ[v][0:32] = h@Wa, PQ[v][32:64] = h@Wb ---------------
__global__ __launch_bounds__(256) void k_pq2(const float* __restrict__ H,
                                             const float* __restrict__ We,
                                             float* __restrict__ PQ, int n) {
  const int ROWS = 32;
  __shared__ float hsm[ROWS][128];
  __shared__ float wl[128][64];
  int r0 = blockIdx.x * ROWS;
  int col = threadIdx.x & 63;
  int rg = threadIdx.x >> 6;  // 0..3
  for (int idx = threadIdx.x; idx < 1024; idx += 256) {
    int r = idx >> 5, k4 = idx & 31;
    int gr = r0 + r;
    float4 v = make_float4(0.f, 0.f, 0.f, 0.f);
    if (gr < n) v = ((const float4*)(H + (size_t)gr * 128))[k4];
    ((float4*)hsm[r])[k4] = v;
  }
  for (int idx = threadIdx.x; idx < 2048; idx += 256) {
    int k = idx >> 4, c4 = idx & 15;
    int c = c4 * 4;
    float4 v;
    if (c < 32)
      v = *(const float4*)(We + (size_t)k * 32 + c);
    else
      v = *(const float4*)(We + (size_t)(128 + k) * 32 + (c - 32));
    ((float4*)wl[k])[c4] = v;
  }
  __syncthreads();
  float acc[8];
  #pragma unroll
  for (int i = 0; i < 8; i++) acc[i] = 0.f;
  #pragma unroll 4
  for (int kk = 0; kk < 128; kk += 4) {
    float w0 = wl[kk + 0][col];
    float w1 = wl[kk + 1][col];
    float w2 = wl[kk + 2][col];
    float w3 = wl[kk + 3][col];
    #pragma unroll
    for (int r = 0; r < 8; r++) {
      float4 xv = *(const float4*)&hsm[rg * 8 + r][kk];
      acc[r] += xv.x * w0 + xv.y * w1 + xv.z * w2 + xv.w * w3;
    }
  }
  #pragma unroll
  for (int r = 0; r < 8; r++) {
    int gr = r0 + rg * 8 + r;
    if (gr < n) PQ[(size_t)gr * 64 + col] = acc[r];
  }
}

// ---------------- edge: out[e] = P[src] + Q[dst] + ea[e]@Wc + b -------------
__global__ __launch_bounds__(256) void k_edge4(const int* __restrict__ src,
                                               const int* __restrict__ dst,
                                               const float* __restrict__ ea,
                                               const float* __restrict__ PQ,
                                               const float* __restrict__ We,
                                               const float* __restrict__ be,
                                               float* __restrict__ out, int ne) {
  __shared__ int sidx[64];
  __shared__ int didx[64];
  __shared__ float eas[64][16];
  __shared__ float wcs[16][32];
  __shared__ float bes[32];
  int tid = threadIdx.x;
  int ebase = blockIdx.x * 64;  // NE % 64 == 0
  if (tid < 128)
    ((float4*)wcs)[tid] = ((const float4*)(We + 256 * 32))[tid];
  if (tid < 32) bes[tid] = be[tid];
  if (tid >= 128 && tid < 192) sidx[tid - 128] = src[ebase + tid - 128];
  if (tid >= 192)              didx[tid - 192] = dst[ebase + tid - 192];
  {
    int row = tid >> 2, q = tid & 3;
    ((float4*)eas[row])[q] = ((const float4*)(ea + (size_t)(ebase + row) * 16))[q];
  }
  __syncthreads();
  int j = tid & 31;
  int grp = tid >> 5;  // 0..7
  float pv[8], qv[8];
  int el[8];
  #pragma unroll
  for (int u = 0; u < 8; u++) el[u] = u * 8 + grp;
  #pragma unroll
  for (int u = 0; u < 8; u++) {
    int s = sidx[el[u]];
    int d = didx[el[u]];
    pv[u] = PQ[(size_t)s * 64 + j];
    qv[u] = PQ[(size_t)d * 64 + 32 + j];
  }
  #pragma unroll
  for (int u = 0; u < 8; u++) {
    int e = ebase + el[u];
    float acc = pv[u] + qv[u] + bes[j];
    #pragma unroll
    for (int k = 0; k < 16; k++)
      acc += eas[el[u]][k] * wcs[k][j];
    out[(size_t)e * 32 + j] = acc;
  }
}

extern "C" void kernel_launch(void* const* d_in, const int* in_sizes, int n_in,
                              void* d_out, int out_size, void* d_ws, size_t ws_size,
                              hipStream_t stream) {
  const float* x  = (const float*)d_in[0];
  const int*   ei = (const int*)d_in[1];
  const float* ea = (const float*)d_in[2];
  const float* W1 = (const float*)d_in[3];
  const float* b1 = (const float*)d_in[4];
  const float* W2 = (const float*)d_in[5];
  const float* b2 = (const float*)d_in[6];
  const float* We = (const float*)d_in[7];
  const float* be = (const float*)d_in[8];
  float* out = (float*)d_out;
  const int* src = ei;
  const int* dst = ei + NE;

  char* w = (char*)d_ws;
  auto alloc = [&](size_t b) {
    void* p = (void*)w;
    w += (b + 255) & ~(size_t)255;
    return p;
  };
  int* cnt    = (int*)alloc(NN * 4);
  int* cur    = (int*)alloc(NN * 4);
  int* offs   = (int*)alloc((NN + 1) * 4);
  int* bsum   = (int*)alloc(256 * 4);
  int* adj    = (int*)alloc((size_t)NE * 4);
  float* dinv = (float*)alloc(NN * 4);
  unsigned* xs  = (unsigned*)alloc((size_t)NN * 32 * 4);   // bf16 [NN][64]
  unsigned* h1s = (unsigned*)alloc((size_t)NN * 64 * 4);   // bf16 [NN][128]
  float* z    = (float*)alloc((size_t)NN * 128 * 4);       // z1 [NN][64] then z2 [NN][128]
  float* h2   = (float*)alloc((size_t)NN * 128 * 4);       // f32 [NN][128]
  float* pq   = (float*)h1s;  // reuse: h1s dead after agg128; pq live after

  const int nblkN = (NN + 255) / 256;   // 196
  const int nblkE = (NE + 255) / 256;

  k_zero<<<nblkN, 256, 0, stream>>>(cnt, cur, NN);
  k_count<<<nblkE, 256, 0, stream>>>(dst, cnt, NE);
  k_scan1<<<nblkN, 256, 0, stream>>>(cnt, offs, bsum, NN);
  k_scan2<<<1, 256, 0, stream>>>(bsum, offs + NN, nblkN);
  k_scan3_dinv<<<nblkN, 256, 0, stream>>>(offs, bsum, cnt, dinv, NN);
  k_fill<<<nblkE, 256, 0, stream>>>(src, dst, offs, cur, adj, NE);

  k_prescale<<<(NN * 32 + 255) / 256, 256, 0, stream>>>(x, dinv, xs, NN);
  k_agg64<<<(NN + 7) / 8, 256, 0, stream>>>(xs, offs, adj, dinv, z, NN);

  const int gemmBlk = (NN + 31) / 32;  // 1563
  k_gemm3<64, 0><<<gemmBlk, 256, 0, stream>>>(z, W1, b1, dinv, nullptr, h1s, NN);
  k_agg128<<<(NN + 3) / 4, 256, 0, stream>>>(h1s, offs, adj, dinv, z, NN);
  k_gemm3<128, 1><<<gemmBlk, 256, 0, stream>>>(z, W2, b2, nullptr, h2, nullptr, NN);

  k_pq2<<<gemmBlk, 256, 0, stream>>>(h2, We, pq, NN);
  k_edge4<<<NE / 64, 256, 0, stream>>>(src, dst, ea, pq, We, be, out, NE);
}

// Round 9
// 281.318 us; speedup vs baseline: 13.0250x; 1.1914x over previous
//
#include <hip/hip_runtime.h>

#define NN 50000
#define NE 800000

typedef __attribute__((ext_vector_type(8))) short short8v;
typedef __attribute__((ext_vector_type(4))) float f32x4;

// ---------------- bf16 helpers ----------------
__device__ __forceinline__ float bf_lo(unsigned u) { return __uint_as_float(u << 16); }
__device__ __forceinline__ float bf_hi(unsigned u) { return __uint_as_float(u & 0xffff0000u); }
__device__ __forceinline__ unsigned pack_bf2(float a, float b) {
  unsigned ua = __float_as_uint(a);
  ua = (ua + 0x7fffu + ((ua >> 16) & 1u)) >> 16;
  unsigned ub = __float_as_uint(b);
  ub = (ub + 0x7fffu + ((ub >> 16) & 1u)) & 0xffff0000u;
  return ua | ub;
}
__device__ __forceinline__ unsigned short bf16r(float f) {
  unsigned u = __float_as_uint(f);
  u = (u + 0x7fffu + ((u >> 16) & 1u)) >> 16;
  return (unsigned short)u;
}

// ---------------- CSR build ----------------
__global__ void k_zero(int* cnt, int* cur, int n) {
  int i = blockIdx.x * blockDim.x + threadIdx.x;
  if (i < n) { cnt[i] = 0; cur[i] = 0; }
}

__global__ void k_count(const int* dst, int* cnt, int e) {
  int i = blockIdx.x * blockDim.x + threadIdx.x;
  if (i < e) atomicAdd(&cnt[dst[i]], 1);
}

__global__ void k_scan1(const int* cnt, int* offs, int* bsum, int n) {
  __shared__ int s[256];
  int i = blockIdx.x * 256 + threadIdx.x;
  int v = (i < n) ? cnt[i] : 0;
  s[threadIdx.x] = v;
  __syncthreads();
  #pragma unroll
  for (int d = 1; d < 256; d <<= 1) {
    int t = (threadIdx.x >= d) ? s[threadIdx.x - d] : 0;
    __syncthreads();
    s[threadIdx.x] += t;
    __syncthreads();
  }
  if (i < n) offs[i] = s[threadIdx.x] - v;
  if (threadIdx.x == 255) bsum[blockIdx.x] = s[255];
}

__global__ void k_scan2(int* bsum, int* offsN, int nb) {
  __shared__ int s[256];
  int v = (threadIdx.x < nb) ? bsum[threadIdx.x] : 0;
  s[threadIdx.x] = v;
  __syncthreads();
  #pragma unroll
  for (int d = 1; d < 256; d <<= 1) {
    int t = (threadIdx.x >= d) ? s[threadIdx.x - d] : 0;
    __syncthreads();
    s[threadIdx.x] += t;
    __syncthreads();
  }
  if (threadIdx.x < nb) bsum[threadIdx.x] = s[threadIdx.x] - v;
  if (threadIdx.x == 255) *offsN = s[255];
}

__global__ void k_scan3_dinv(int* offs, const int* bsum, const int* cnt,
                             float* dinv, int n) {
  int i = blockIdx.x * blockDim.x + threadIdx.x;
  if (i < n) {
    offs[i] += bsum[i >> 8];
    dinv[i] = rsqrtf((float)(cnt[i] + 1));
  }
}

__global__ void k_fill(const int* src, const int* dst, const int* offs,
                       int* cur, int* adj, int e) {
  int i = blockIdx.x * blockDim.x + threadIdx.x;
  if (i < e) {
    int d = dst[i];
    int pos = atomicAdd(&cur[d], 1);
    adj[offs[d] + pos] = src[i];
  }
}

// ---------------- weight prep: bf16, transposed (Wt[c][k] = W[k][c]) -------
__global__ void k_prepw(const float* __restrict__ W1, const float* __restrict__ W2,
                        unsigned short* __restrict__ W1t,
                        unsigned short* __restrict__ W2t) {
  int i = blockIdx.x * 256 + threadIdx.x;
  if (i < 8192)  { int c = i >> 6, k = i & 63;  W1t[i] = bf16r(W1[k * 128 + c]); }
  if (i < 16384) { int c = i >> 7, k = i & 127; W2t[i] = bf16r(W2[k * 128 + c]); }
}

// ---------------- prescale: xs[v] = bf16(dinv[v] * x[v]) (64 dims) ----------
__global__ void k_prescale(const float* __restrict__ x,
                           const float* __restrict__ dinv,
                           unsigned* __restrict__ xs, int n) {
  int i = blockIdx.x * blockDim.x + threadIdx.x;  // over n*32
  if (i >= n * 32) return;
  int v = i >> 5, c2 = i & 31;
  float d = dinv[v];
  float2 xv = ((const float2*)(x + (size_t)v * 64))[c2];
  xs[(size_t)v * 32 + c2] = pack_bf2(xv.x * d, xv.y * d);
}

// ---------------- agg64: z[v] = bf16(dinv[v]*(xs[v] + sum xs[src])) ---------
// half-wave (32 lanes) per node; bf16 in, bf16 out
__global__ void k_agg64(const unsigned* __restrict__ xs,
                        const int* __restrict__ offs, const int* __restrict__ adj,
                        const float* __restrict__ dinv, unsigned* __restrict__ z,
                        int n) {
  int node = blockIdx.x * 8 + (threadIdx.x >> 5);
  if (node >= n) return;
  int lane = threadIdx.x & 31;
  float ax[8], ay[8];
  {
    unsigned u = xs[(size_t)node * 32 + lane];
    ax[0] = bf_lo(u); ay[0] = bf_hi(u);
  }
  #pragma unroll
  for (int u = 1; u < 8; u++) { ax[u] = 0.f; ay[u] = 0.f; }
  int s = offs[node], e = offs[node + 1];
  int i = s;
  for (; i + 8 <= e; i += 8) {
    int idx[8];
    #pragma unroll
    for (int u = 0; u < 8; u++) idx[u] = adj[i + u];
    #pragma unroll
    for (int u = 0; u < 8; u++) {
      unsigned uv = xs[(size_t)idx[u] * 32 + lane];
      ax[u] += bf_lo(uv); ay[u] += bf_hi(uv);
    }
  }
  for (; i < e; i++) {
    unsigned uv = xs[(size_t)adj[i] * 32 + lane];
    ax[0] += bf_lo(uv); ay[0] += bf_hi(uv);
  }
  float sx = ((ax[0] + ax[1]) + (ax[2] + ax[3])) + ((ax[4] + ax[5]) + (ax[6] + ax[7]));
  float sy = ((ay[0] + ay[1]) + (ay[2] + ay[3])) + ((ay[4] + ay[5]) + (ay[6] + ay[7]));
  float d = dinv[node];
  z[(size_t)node * 32 + lane] = pack_bf2(sx * d, sy * d);
}

// ---------------- agg128: z[v] = bf16(dinv[v]*(hs[v] + sum hs[src])) --------
__global__ void k_agg128(const unsigned* __restrict__ hs,
                         const int* __restrict__ offs, const int* __restrict__ adj,
                         const float* __restrict__ dinv, unsigned* __restrict__ z,
                         int n) {
  int node = blockIdx.x * 4 + (threadIdx.x >> 6);
  if (node >= n) return;
  int lane = threadIdx.x & 63;
  float ax[8], ay[8];
  {
    unsigned u = hs[(size_t)node * 64 + lane];
    ax[0] = bf_lo(u); ay[0] = bf_hi(u);
  }
  #pragma unroll
  for (int u = 1; u < 8; u++) { ax[u] = 0.f; ay[u] = 0.f; }
  int s = offs[node], e = offs[node + 1];
  int i = s;
  for (; i + 8 <= e; i += 8) {
    int idx[8];
    #pragma unroll
    for (int u = 0; u < 8; u++) idx[u] = adj[i + u];
    #pragma unroll
    for (int u = 0; u < 8; u++) {
      unsigned uv = hs[(size_t)idx[u] * 64 + lane];
      ax[u] += bf_lo(uv); ay[u] += bf_hi(uv);
    }
  }
  for (; i < e; i++) {
    unsigned uv = hs[(size_t)adj[i] * 64 + lane];
    ax[0] += bf_lo(uv); ay[0] += bf_hi(uv);
  }
  float sx = ((ax[0] + ax[1]) + (ax[2] + ax[3])) + ((ax[4] + ax[5]) + (ax[6] + ax[7]));
  float sy = ((ay[0] + ay[1]) + (ay[2] + ay[3])) + ((ay[4] + ay[5]) + (ay[6] + ay[7]));
  float d = dinv[node];
  z[(size_t)node * 64 + lane] = pack_bf2(sx * d, sy * d);
}

// ---------------- MFMA GEMM: out = relu(A@W + b), A bf16 [n][K], Wt bf16 ----
// Block = 4 waves = 2 row-tiles x 2 col-halves -> 32 rows x 128 cols.
// Per wave: 16 rows x 64 cols = 4 col-tiles of 16x16x32 MFMA.
// A frag: row = lane&15, k = (lane>>4)*8 + [0..8)
// B frag: col = lane&15, same k (Wt is [col][k] so this is contiguous)
// C/D:    col = lane&15, row = (lane>>4)*4 + reg    [verified m89]
// EPI 0: store bf16 scaled by dinv[row] (next-layer gather input)
// EPI 1: store f32
template <int K, int EPI>
__global__ __launch_bounds__(256) void k_mgemm(const unsigned short* __restrict__ A,
                                               const unsigned short* __restrict__ Bt,
                                               const float* __restrict__ bias,
                                               const float* __restrict__ dinv,
                                               float* __restrict__ outf,
                                               unsigned short* __restrict__ outb,
                                               int n) {
  int lane = threadIdx.x & 63;
  int wid = threadIdx.x >> 6;   // 0..3
  int wr = wid >> 1;            // 0..1 row-tile
  int wc = wid & 1;             // 0..1 col-half
  int r0 = blockIdx.x * 32 + wr * 16;
  int cbase = wc * 64;
  int lr = lane & 15;
  int lk = (lane >> 4) * 8;
  int arow = r0 + lr;
  if (arow >= n) arow = n - 1;
  const unsigned short* arp = A + (size_t)arow * K + lk;
  f32x4 acc[4];
  #pragma unroll
  for (int ct = 0; ct < 4; ct++) acc[ct] = (f32x4){0.f, 0.f, 0.f, 0.f};
  #pragma unroll
  for (int ks = 0; ks < K; ks += 32) {
    short8v a = *reinterpret_cast<const short8v*>(arp + ks);
    #pragma unroll
    for (int ct = 0; ct < 4; ct++) {
      const unsigned short* bp = Bt + (size_t)(cbase + ct * 16 + lr) * K + lk + ks;
      short8v b = *reinterpret_cast<const short8v*>(bp);
      acc[ct] = __builtin_amdgcn_mfma_f32_16x16x32_bf16(a, b, acc[ct], 0, 0, 0);
    }
  }
  int rbase = r0 + (lane >> 4) * 4;
  #pragma unroll
  for (int ct = 0; ct < 4; ct++) {
    int col = cbase + ct * 16 + lr;
    float bv = bias[col];
    #pragma unroll
    for (int rg = 0; rg < 4; rg++) {
      int row = rbase + rg;
      if (row >= n) continue;
      float v = fmaxf(acc[ct][rg] + bv, 0.f);
      if (EPI == 0) {
        outb[(size_t)row * 128 + col] = bf16r(v * dinv[row]);
      } else {
        outf[(size_t)row * 128 + col] = v;
      }
    }
  }
}

// ---------------- PQ: PQ[v][0:32] = h@Wa, PQ[v][32:64] = h@Wb ---------------
__global__ __launch_bounds__(256) void k_pq2(const float* __restrict__ H,
                                             const float* __restrict__ We,
                                             float* __restrict__ PQ, int n) {
  const int ROWS = 32;
  __shared__ float hsm[ROWS][128];
  __shared__ float wl[128][64];
  int r0 = blockIdx.x * ROWS;
  int col = threadIdx.x & 63;
  int rg = threadIdx.x >> 6;  // 0..3
  for (int idx = threadIdx.x; idx < 1024; idx += 256) {
    int r = idx >> 5, k4 = idx & 31;
    int gr = r0 + r;
    float4 v = make_float4(0.f, 0.f, 0.f, 0.f);
    if (gr < n) v = ((const float4*)(H + (size_t)gr * 128))[k4];
    ((float4*)hsm[r])[k4] = v;
  }
  for (int idx = threadIdx.x; idx < 2048; idx += 256) {
    int k = idx >> 4, c4 = idx & 15;
    int c = c4 * 4;
    float4 v;
    if (c < 32)
      v = *(const float4*)(We + (size_t)k * 32 + c);
    else
      v = *(const float4*)(We + (size_t)(128 + k) * 32 + (c - 32));
    ((float4*)wl[k])[c4] = v;
  }
  __syncthreads();
  float acc[8];
  #pragma unroll
  for (int i = 0; i < 8; i++) acc[i] = 0.f;
  #pragma unroll 4
  for (int kk = 0; kk < 128; kk += 4) {
    float w0 = wl[kk + 0][col];
    float w1 = wl[kk + 1][col];
    float w2 = wl[kk + 2][col];
    float w3 = wl[kk + 3][col];
    #pragma unroll
    for (int r = 0; r < 8; r++) {
      float4 xv = *(const float4*)&hsm[rg * 8 + r][kk];
      acc[r] += xv.x * w0 + xv.y * w1 + xv.z * w2 + xv.w * w3;
    }
  }
  #pragma unroll
  for (int r = 0; r < 8; r++) {
    int gr = r0 + rg * 8 + r;
    if (gr < n) PQ[(size_t)gr * 64 + col] = acc[r];
  }
}

// ---------------- edge: out[e] = P[src] + Q[dst] + ea[e]@Wc + b -------------
__global__ __launch_bounds__(256) void k_edge4(const int* __restrict__ src,
                                               const int* __restrict__ dst,
                                               const float* __restrict__ ea,
                                               const float* __restrict__ PQ,
                                               const float* __restrict__ We,
                                               const float* __restrict__ be,
                                               float* __restrict__ out, int ne) {
  __shared__ int sidx[64];
  __shared__ int didx[64];
  __shared__ float eas[64][16];
  __shared__ float wcs[16][32];
  __shared__ float bes[32];
  int tid = threadIdx.x;
  int ebase = blockIdx.x * 64;  // NE % 64 == 0
  if (tid < 128)
    ((float4*)wcs)[tid] = ((const float4*)(We + 256 * 32))[tid];
  if (tid < 32) bes[tid] = be[tid];
  if (tid >= 128 && tid < 192) sidx[tid - 128] = src[ebase + tid - 128];
  if (tid >= 192)              didx[tid - 192] = dst[ebase + tid - 192];
  {
    int row = tid >> 2, q = tid & 3;
    ((float4*)eas[row])[q] = ((const float4*)(ea + (size_t)(ebase + row) * 16))[q];
  }
  __syncthreads();
  int j = tid & 31;
  int grp = tid >> 5;  // 0..7
  float pv[8], qv[8];
  int el[8];
  #pragma unroll
  for (int u = 0; u < 8; u++) el[u] = u * 8 + grp;
  #pragma unroll
  for (int u = 0; u < 8; u++) {
    int s = sidx[el[u]];
    int d = didx[el[u]];
    pv[u] = PQ[(size_t)s * 64 + j];
    qv[u] = PQ[(size_t)d * 64 + 32 + j];
  }
  #pragma unroll
  for (int u = 0; u < 8; u++) {
    int e = ebase + el[u];
    float acc = pv[u] + qv[u] + bes[j];
    #pragma unroll
    for (int k = 0; k < 16; k++)
      acc += eas[el[u]][k] * wcs[k][j];
    out[(size_t)e * 32 + j] = acc;
  }
}

extern "C" void kernel_launch(void* const* d_in, const int* in_sizes, int n_in,
                              void* d_out, int out_size, void* d_ws, size_t ws_size,
                              hipStream_t stream) {
  const float* x  = (const float*)d_in[0];
  const int*   ei = (const int*)d_in[1];
  const float* ea = (const float*)d_in[2];
  const float* W1 = (const float*)d_in[3];
  const float* b1 = (const float*)d_in[4];
  const float* W2 = (const float*)d_in[5];
  const float* b2 = (const float*)d_in[6];
  const float* We = (const float*)d_in[7];
  const float* be = (const float*)d_in[8];
  float* out = (float*)d_out;
  const int* src = ei;
  const int* dst = ei + NE;

  char* w = (char*)d_ws;
  auto alloc = [&](size_t b) {
    void* p = (void*)w;
    w += (b + 255) & ~(size_t)255;
    return p;
  };
  int* cnt    = (int*)alloc(NN * 4);
  int* cur    = (int*)alloc(NN * 4);
  int* offs   = (int*)alloc((NN + 1) * 4);
  int* bsum   = (int*)alloc(256 * 4);
  int* adj    = (int*)alloc((size_t)NE * 4);
  float* dinv = (float*)alloc(NN * 4);
  unsigned* xs  = (unsigned*)alloc((size_t)NN * 32 * 4);   // bf16 [NN][64]
  unsigned* h1s = (unsigned*)alloc((size_t)NN * 64 * 4);   // bf16 [NN][128]
  unsigned* z12 = (unsigned*)alloc((size_t)NN * 64 * 4);   // bf16 z1[NN][64] then z2[NN][128]
  float* h2   = (float*)alloc((size_t)NN * 128 * 4);       // f32 [NN][128]
  unsigned short* w1t = (unsigned short*)alloc(8192 * 2);  // bf16 [128c][64k]
  unsigned short* w2t = (unsigned short*)alloc(16384 * 2); // bf16 [128c][128k]
  float* pq   = (float*)h1s;  // reuse: h1s dead after agg128

  const int nblkN = (NN + 255) / 256;   // 196
  const int nblkE = (NE + 255) / 256;

  k_zero<<<nblkN, 256, 0, stream>>>(cnt, cur, NN);
  k_count<<<nblkE, 256, 0, stream>>>(dst, cnt, NE);
  k_scan1<<<nblkN, 256, 0, stream>>>(cnt, offs, bsum, NN);
  k_scan2<<<1, 256, 0, stream>>>(bsum, offs + NN, nblkN);
  k_scan3_dinv<<<nblkN, 256, 0, stream>>>(offs, bsum, cnt, dinv, NN);
  k_fill<<<nblkE, 256, 0, stream>>>(src, dst, offs, cur, adj, NE);

  k_prepw<<<64, 256, 0, stream>>>(W1, W2, w1t, w2t);
  k_prescale<<<(NN * 32 + 255) / 256, 256, 0, stream>>>(x, dinv, xs, NN);
  k_agg64<<<(NN + 7) / 8, 256, 0, stream>>>(xs, offs, adj, dinv, z12, NN);

  const int mgBlk = (NN + 31) / 32;  // 1563
  k_mgemm<64, 0><<<mgBlk, 256, 0, stream>>>((const unsigned short*)z12, w1t, b1,
                                            dinv, nullptr, (unsigned short*)h1s, NN);
  k_agg128<<<(NN + 3) / 4, 256, 0, stream>>>(h1s, offs, adj, dinv, z12, NN);
  k_mgemm<128, 1><<<mgBlk, 256, 0, stream>>>((const unsigned short*)z12, w2t, b2,
                                             nullptr, h2, nullptr, NN);

  k_pq2<<<mgBlk, 256, 0, stream>>>(h2, We, pq, NN);
  k_edge4<<<NE / 64, 256, 0, stream>>>(src, dst, ea, pq, We, be, out, NE);
}

// Round 10
// 243.854 us; speedup vs baseline: 15.0261x; 1.1536x over previous
//
#include <hip/hip_runtime.h>

#define NN 50000
#define NE 800000

typedef __attribute__((ext_vector_type(8))) short short8v;
typedef __attribute__((ext_vector_type(4))) float f32x4;

// ---------------- bf16 helpers ----------------
__device__ __forceinline__ float bf_lo(unsigned u) { return __uint_as_float(u << 16); }
__device__ __forceinline__ float bf_hi(unsigned u) { return __uint_as_float(u & 0xffff0000u); }
__device__ __forceinline__ unsigned pack_bf2(float a, float b) {
  unsigned ua = __float_as_uint(a);
  ua = (ua + 0x7fffu + ((ua >> 16) & 1u)) >> 16;
  unsigned ub = __float_as_uint(b);
  ub = (ub + 0x7fffu + ((ub >> 16) & 1u)) & 0xffff0000u;
  return ua | ub;
}
__device__ __forceinline__ unsigned short bf16r(float f) {
  unsigned u = __float_as_uint(f);
  u = (u + 0x7fffu + ((u >> 16) & 1u)) >> 16;
  return (unsigned short)u;
}

// ---------------- prep0: zero counters + bf16/transposed weights ------------
// W1t[c][k]=W1[k][c] (128x64), W2t[c][k]=W2[k][c] (128x128),
// Wabt[c][k]: c<32 -> Wa[k][c]=We[k*32+c]; c>=32 -> Wb[k][c-32]=We[(128+k)*32+c-32]
__global__ void k_prep0(const float* __restrict__ W1, const float* __restrict__ W2,
                        const float* __restrict__ We,
                        unsigned short* __restrict__ W1t,
                        unsigned short* __restrict__ W2t,
                        unsigned short* __restrict__ Wabt,
                        int* cnt, int* cur) {
  int i = blockIdx.x * 256 + threadIdx.x;
  if (i < NN) { cnt[i] = 0; cur[i] = 0; }
  if (i < 8192)  { int c = i >> 6, k = i & 63;  W1t[i] = bf16r(W1[k * 128 + c]); }
  if (i < 16384) { int c = i >> 7, k = i & 127; W2t[i] = bf16r(W2[k * 128 + c]); }
  if (i < 8192) {
    int c = i >> 7, k = i & 127;
    float v = (c < 32) ? We[k * 32 + c] : We[(128 + k) * 32 + (c - 32)];
    Wabt[i] = bf16r(v);
  }
}

// ---------------- CSR build ----------------
__global__ void k_count(const int* dst, int* cnt, int e) {
  int i = blockIdx.x * blockDim.x + threadIdx.x;
  if (i < e) atomicAdd(&cnt[dst[i]], 1);
}

__global__ void k_scan1(const int* cnt, int* offs, int* bsum, int n) {
  __shared__ int s[256];
  int i = blockIdx.x * 256 + threadIdx.x;
  int v = (i < n) ? cnt[i] : 0;
  s[threadIdx.x] = v;
  __syncthreads();
  #pragma unroll
  for (int d = 1; d < 256; d <<= 1) {
    int t = (threadIdx.x >= d) ? s[threadIdx.x - d] : 0;
    __syncthreads();
    s[threadIdx.x] += t;
    __syncthreads();
  }
  if (i < n) offs[i] = s[threadIdx.x] - v;
  if (threadIdx.x == 255) bsum[blockIdx.x] = s[255];
}

__global__ void k_scan2(int* bsum, int* offsN, int nb) {
  __shared__ int s[256];
  int v = (threadIdx.x < nb) ? bsum[threadIdx.x] : 0;
  s[threadIdx.x] = v;
  __syncthreads();
  #pragma unroll
  for (int d = 1; d < 256; d <<= 1) {
    int t = (threadIdx.x >= d) ? s[threadIdx.x - d] : 0;
    __syncthreads();
    s[threadIdx.x] += t;
    __syncthreads();
  }
  if (threadIdx.x < nb) bsum[threadIdx.x] = s[threadIdx.x] - v;
  if (threadIdx.x == 255) *offsN = s[255];
}

__global__ void k_scan3_dinv(int* offs, const int* bsum, const int* cnt,
                             float* dinv, int n) {
  int i = blockIdx.x * blockDim.x + threadIdx.x;
  if (i < n) {
    offs[i] += bsum[i >> 8];
    dinv[i] = rsqrtf((float)(cnt[i] + 1));
  }
}

__global__ void k_fill(const int* src, const int* dst, const int* offs,
                       int* cur, int* adj, int e) {
  int i = blockIdx.x * blockDim.x + threadIdx.x;
  if (i < e) {
    int d = dst[i];
    int pos = atomicAdd(&cur[d], 1);
    adj[offs[d] + pos] = src[i];
  }
}

// ---------------- prescale: xs[v] = bf16(dinv[v] * x[v]) (64 dims) ----------
__global__ void k_prescale(const float* __restrict__ x,
                           const float* __restrict__ dinv,
                           unsigned* __restrict__ xs, int n) {
  int i = blockIdx.x * blockDim.x + threadIdx.x;
  if (i >= n * 32) return;
  int v = i >> 5, c2 = i & 31;
  float d = dinv[v];
  float2 xv = ((const float2*)(x + (size_t)v * 64))[c2];
  xs[(size_t)v * 32 + c2] = pack_bf2(xv.x * d, xv.y * d);
}

// ---------------- agg64: z[v] = bf16(dinv[v]*(xs[v] + sum xs[src])) ---------
__global__ void k_agg64(const unsigned* __restrict__ xs,
                        const int* __restrict__ offs, const int* __restrict__ adj,
                        const float* __restrict__ dinv, unsigned* __restrict__ z,
                        int n) {
  int node = blockIdx.x * 8 + (threadIdx.x >> 5);
  if (node >= n) return;
  int lane = threadIdx.x & 31;
  float ax[8], ay[8];
  {
    unsigned u = xs[(size_t)node * 32 + lane];
    ax[0] = bf_lo(u); ay[0] = bf_hi(u);
  }
  #pragma unroll
  for (int u = 1; u < 8; u++) { ax[u] = 0.f; ay[u] = 0.f; }
  int s = offs[node], e = offs[node + 1];
  int i = s;
  for (; i + 8 <= e; i += 8) {
    int idx[8];
    #pragma unroll
    for (int u = 0; u < 8; u++) idx[u] = adj[i + u];
    #pragma unroll
    for (int u = 0; u < 8; u++) {
      unsigned uv = xs[(size_t)idx[u] * 32 + lane];
      ax[u] += bf_lo(uv); ay[u] += bf_hi(uv);
    }
  }
  for (; i < e; i++) {
    unsigned uv = xs[(size_t)adj[i] * 32 + lane];
    ax[0] += bf_lo(uv); ay[0] += bf_hi(uv);
  }
  float sx = ((ax[0] + ax[1]) + (ax[2] + ax[3])) + ((ax[4] + ax[5]) + (ax[6] + ax[7]));
  float sy = ((ay[0] + ay[1]) + (ay[2] + ay[3])) + ((ay[4] + ay[5]) + (ay[6] + ay[7]));
  float d = dinv[node];
  z[(size_t)node * 32 + lane] = pack_bf2(sx * d, sy * d);
}

// ---------------- agg128: z[v] = bf16(dinv[v]*(hs[v] + sum hs[src])) --------
__global__ void k_agg128(const unsigned* __restrict__ hs,
                         const int* __restrict__ offs, const int* __restrict__ adj,
                         const float* __restrict__ dinv, unsigned* __restrict__ z,
                         int n) {
  int node = blockIdx.x * 4 + (threadIdx.x >> 6);
  if (node >= n) return;
  int lane = threadIdx.x & 63;
  float ax[8], ay[8];
  {
    unsigned u = hs[(size_t)node * 64 + lane];
    ax[0] = bf_lo(u); ay[0] = bf_hi(u);
  }
  #pragma unroll
  for (int u = 1; u < 8; u++) { ax[u] = 0.f; ay[u] = 0.f; }
  int s = offs[node], e = offs[node + 1];
  int i = s;
  for (; i + 8 <= e; i += 8) {
    int idx[8];
    #pragma unroll
    for (int u = 0; u < 8; u++) idx[u] = adj[i + u];
    #pragma unroll
    for (int u = 0; u < 8; u++) {
      unsigned uv = hs[(size_t)idx[u] * 64 + lane];
      ax[u] += bf_lo(uv); ay[u] += bf_hi(uv);
    }
  }
  for (; i < e; i++) {
    unsigned uv = hs[(size_t)adj[i] * 64 + lane];
    ax[0] += bf_lo(uv); ay[0] += bf_hi(uv);
  }
  float sx = ((ax[0] + ax[1]) + (ax[2] + ax[3])) + ((ax[4] + ax[5]) + (ax[6] + ax[7]));
  float sy = ((ay[0] + ay[1]) + (ay[2] + ay[3])) + ((ay[4] + ay[5]) + (ay[6] + ay[7]));
  float d = dinv[node];
  z[(size_t)node * 64 + lane] = pack_bf2(sx * d, sy * d);
}

// ---------------- MFMA GEMM layer1: h1 = bf16(dinv*relu(z1@W1+b1)) ----------
// Block = 4 waves = 2 row-tiles x 2 col-halves -> 32 rows x 128 cols.
template <int K>
__global__ __launch_bounds__(256) void k_mgemm(const unsigned short* __restrict__ A,
                                               const unsigned short* __restrict__ Bt,
                                               const float* __restrict__ bias,
                                               const float* __restrict__ dinv,
                                               unsigned short* __restrict__ outb,
                                               int n) {
  int lane = threadIdx.x & 63;
  int wid = threadIdx.x >> 6;
  int wr = wid >> 1, wc = wid & 1;
  int r0 = blockIdx.x * 32 + wr * 16;
  int cbase = wc * 64;
  int lr = lane & 15;
  int lk = (lane >> 4) * 8;
  int arow = r0 + lr;
  if (arow >= n) arow = n - 1;
  const unsigned short* arp = A + (size_t)arow * K + lk;
  f32x4 acc[4];
  #pragma unroll
  for (int ct = 0; ct < 4; ct++) acc[ct] = (f32x4){0.f, 0.f, 0.f, 0.f};
  #pragma unroll
  for (int ks = 0; ks < K; ks += 32) {
    short8v a = *reinterpret_cast<const short8v*>(arp + ks);
    #pragma unroll
    for (int ct = 0; ct < 4; ct++) {
      const unsigned short* bp = Bt + (size_t)(cbase + ct * 16 + lr) * K + lk + ks;
      short8v b = *reinterpret_cast<const short8v*>(bp);
      acc[ct] = __builtin_amdgcn_mfma_f32_16x16x32_bf16(a, b, acc[ct], 0, 0, 0);
    }
  }
  int rbase = r0 + (lane >> 4) * 4;
  #pragma unroll
  for (int ct = 0; ct < 4; ct++) {
    int col = cbase + ct * 16 + lr;
    float bv = bias[col];
    #pragma unroll
    for (int rg = 0; rg < 4; rg++) {
      int row = rbase + rg;
      if (row >= n) continue;
      float v = fmaxf(acc[ct][rg] + bv, 0.f);
      outb[(size_t)row * 128 + col] = bf16r(v * dinv[row]);
    }
  }
}

// ---------------- MFMA GEMM layer2 + fused PQ --------------------------------
// h2 = relu(z2@W2+b2) -> LDS bf16 [32][136] (pad 8 -> 2-way banks only)
// PQ[row][0:32]=h2@Wa, [32:64]=h2@Wb via MFMA on LDS tile; store bf16.
__global__ __launch_bounds__(256) void k_mgemm2pq(
    const unsigned short* __restrict__ A,    // z2 bf16 [n][128]
    const unsigned short* __restrict__ Bt,   // W2t bf16 [128c][128k]
    const unsigned short* __restrict__ Wabt, // bf16 [64c][128k]
    const float* __restrict__ bias,          // b2
    unsigned short* __restrict__ PQb,        // bf16 [n][64]
    int n) {
  __shared__ unsigned short hs[32][136];
  int lane = threadIdx.x & 63;
  int wid = threadIdx.x >> 6;
  int wr = wid >> 1, wc = wid & 1;
  int r0 = blockIdx.x * 32;
  int lr = lane & 15;
  int lk = (lane >> 4) * 8;
  int arow = r0 + wr * 16 + lr;
  if (arow >= n) arow = n - 1;
  const unsigned short* arp = A + (size_t)arow * 128 + lk;
  f32x4 acc[4];
  #pragma unroll
  for (int ct = 0; ct < 4; ct++) acc[ct] = (f32x4){0.f, 0.f, 0.f, 0.f};
  #pragma unroll
  for (int ks = 0; ks < 128; ks += 32) {
    short8v a = *reinterpret_cast<const short8v*>(arp + ks);
    #pragma unroll
    for (int ct = 0; ct < 4; ct++) {
      const unsigned short* bp = Bt + (size_t)(wc * 64 + ct * 16 + lr) * 128 + lk + ks;
      short8v b = *reinterpret_cast<const short8v*>(bp);
      acc[ct] = __builtin_amdgcn_mfma_f32_16x16x32_bf16(a, b, acc[ct], 0, 0, 0);
    }
  }
  // epilogue 1: relu+bias -> LDS tile (bf16)
  int rloc = wr * 16 + (lane >> 4) * 4;
  #pragma unroll
  for (int ct = 0; ct < 4; ct++) {
    int col = wc * 64 + ct * 16 + lr;
    float bv = bias[col];
    #pragma unroll
    for (int rg = 0; rg < 4; rg++)
      hs[rloc + rg][col] = bf16r(fmaxf(acc[ct][rg] + bv, 0.f));
  }
  __syncthreads();
  // epilogue 2: PQ tile 32x64, wave = 16 rows x 32 cols (2 col-tiles), K=128
  f32x4 acc2[2];
  acc2[0] = (f32x4){0.f, 0.f, 0.f, 0.f};
  acc2[1] = (f32x4){0.f, 0.f, 0.f, 0.f};
  #pragma unroll
  for (int ks = 0; ks < 128; ks += 32) {
    short8v a2 = *reinterpret_cast<const short8v*>(&hs[wr * 16 + lr][lk + ks]);
    #pragma unroll
    for (int ct = 0; ct < 2; ct++) {
      const unsigned short* wp = Wabt + (size_t)(wc * 32 + ct * 16 + lr) * 128 + lk + ks;
      short8v b = *reinterpret_cast<const short8v*>(wp);
      acc2[ct] = __builtin_amdgcn_mfma_f32_16x16x32_bf16(a2, b, acc2[ct], 0, 0, 0);
    }
  }
  #pragma unroll
  for (int ct = 0; ct < 2; ct++) {
    int col = wc * 32 + ct * 16 + lr;
    #pragma unroll
    for (int rg = 0; rg < 4; rg++) {
      int row = r0 + wr * 16 + (lane >> 4) * 4 + rg;
      if (row < n) PQb[(size_t)row * 64 + col] = bf16r(acc2[ct][rg]);
    }
  }
}

// ---------------- edge: out[e] = P[src] + Q[dst] + ea[e]@Wc + b -------------
// 64 edges/block; PQ bf16: word l of a row = cols (2l,2l+1).
// 16 groups x 16 lanes; each thread: 4 edges x 2 cols, 8 gathers in flight.
__global__ __launch_bounds__(256) void k_edge5(const int* __restrict__ src,
                                               const int* __restrict__ dst,
                                               const float* __restrict__ ea,
                                               const unsigned* __restrict__ PQw,
                                               const float* __restrict__ We,
                                               const float* __restrict__ be,
                                               float* __restrict__ out, int ne) {
  __shared__ int sidx[64];
  __shared__ int didx[64];
  __shared__ float eas[64][16];
  __shared__ float wcs[16][32];
  __shared__ float bes[32];
  int tid = threadIdx.x;
  int ebase = blockIdx.x * 64;  // NE % 64 == 0
  if (tid < 128)
    ((float4*)wcs)[tid] = ((const float4*)(We + 256 * 32))[tid];
  if (tid < 32) bes[tid] = be[tid];
  if (tid >= 128 && tid < 192) sidx[tid - 128] = src[ebase + tid - 128];
  if (tid >= 192)              didx[tid - 192] = dst[ebase + tid - 192];
  {
    int row = tid >> 2, q = tid & 3;
    ((float4*)eas[row])[q] = ((const float4*)(ea + (size_t)(ebase + row) * 16))[q];
  }
  __syncthreads();
  int l = tid & 15;
  int grp = tid >> 4;  // 0..15
  unsigned pw[4], qw[4];
  int el[4];
  #pragma unroll
  for (int u = 0; u < 4; u++) el[u] = u * 16 + grp;
  #pragma unroll
  for (int u = 0; u < 4; u++) {
    int s = sidx[el[u]];
    int d = didx[el[u]];
    pw[u] = PQw[(size_t)s * 32 + l];
    qw[u] = PQw[(size_t)d * 32 + 16 + l];
  }
  int c0 = 2 * l;
  #pragma unroll
  for (int u = 0; u < 4; u++) {
    int e = ebase + el[u];
    float a0 = bf_lo(pw[u]) + bf_lo(qw[u]) + bes[c0];
    float a1 = bf_hi(pw[u]) + bf_hi(qw[u]) + bes[c0 + 1];
    #pragma unroll
    for (int k = 0; k < 16; k++) {
      float ev = eas[el[u]][k];
      a0 += ev * wcs[k][c0];
      a1 += ev * wcs[k][c0 + 1];
    }
    ((float2*)(out + (size_t)e * 32))[l] = make_float2(a0, a1);
  }
}

extern "C" void kernel_launch(void* const* d_in, const int* in_sizes, int n_in,
                              void* d_out, int out_size, void* d_ws, size_t ws_size,
                              hipStream_t stream) {
  const float* x  = (const float*)d_in[0];
  const int*   ei = (const int*)d_in[1];
  const float* ea = (const float*)d_in[2];
  const float* W1 = (const float*)d_in[3];
  const float* b1 = (const float*)d_in[4];
  const float* W2 = (const float*)d_in[5];
  const float* b2 = (const float*)d_in[6];
  const float* We = (const float*)d_in[7];
  const float* be = (const float*)d_in[8];
  float* out = (float*)d_out;
  const int* src = ei;
  const int* dst = ei + NE;

  char* w = (char*)d_ws;
  auto alloc = [&](size_t b) {
    void* p = (void*)w;
    w += (b + 255) & ~(size_t)255;
    return p;
  };
  int* cnt    = (int*)alloc(NN * 4);
  int* cur    = (int*)alloc(NN * 4);
  int* offs   = (int*)alloc((NN + 1) * 4);
  int* bsum   = (int*)alloc(256 * 4);
  int* adj    = (int*)alloc((size_t)NE * 4);
  float* dinv = (float*)alloc(NN * 4);
  unsigned* xs  = (unsigned*)alloc((size_t)NN * 32 * 4);   // bf16 [NN][64]
  unsigned* h1s = (unsigned*)alloc((size_t)NN * 64 * 4);   // bf16 [NN][128]; later PQ bf16 [NN][64]
  unsigned* z12 = (unsigned*)alloc((size_t)NN * 64 * 4);   // bf16 z1[NN][64] then z2[NN][128]
  unsigned short* w1t  = (unsigned short*)alloc(8192 * 2);  // bf16 [128c][64k]
  unsigned short* w2t  = (unsigned short*)alloc(16384 * 2); // bf16 [128c][128k]
  unsigned short* wabt = (unsigned short*)alloc(8192 * 2);  // bf16 [64c][128k]
  unsigned short* pqb = (unsigned short*)h1s;  // reuse: h1s dead after agg128

  const int nblkN = (NN + 255) / 256;   // 196
  const int nblkE = (NE + 255) / 256;

  k_prep0<<<nblkN, 256, 0, stream>>>(W1, W2, We, w1t, w2t, wabt, cnt, cur);
  k_count<<<nblkE, 256, 0, stream>>>(dst, cnt, NE);
  k_scan1<<<nblkN, 256, 0, stream>>>(cnt, offs, bsum, NN);
  k_scan2<<<1, 256, 0, stream>>>(bsum, offs + NN, nblkN);
  k_scan3_dinv<<<nblkN, 256, 0, stream>>>(offs, bsum, cnt, dinv, NN);
  k_fill<<<nblkE, 256, 0, stream>>>(src, dst, offs, cur, adj, NE);

  k_prescale<<<(NN * 32 + 255) / 256, 256, 0, stream>>>(x, dinv, xs, NN);
  k_agg64<<<(NN + 7) / 8, 256, 0, stream>>>(xs, offs, adj, dinv, z12, NN);

  const int mgBlk = (NN + 31) / 32;  // 1563
  k_mgemm<64><<<mgBlk, 256, 0, stream>>>((const unsigned short*)z12, w1t, b1,
                                         dinv, (unsigned short*)h1s, NN);
  k_agg128<<<(NN + 3) / 4, 256, 0, stream>>>(h1s, offs, adj, dinv, z12, NN);
  k_mgemm2pq<<<mgBlk, 256, 0, stream>>>((const unsigned short*)z12, w2t, wabt,
                                        b2, pqb, NN);
  k_edge5<<<NE / 64, 256, 0, stream>>>(src, dst, ea, (const unsigned*)pqb,
                                       We, be, out, NE);
}

// Round 11
// 239.910 us; speedup vs baseline: 15.2731x; 1.0164x over previous
//
#include <hip/hip_runtime.h>

#define NN 50000
#define NE 800000

typedef __attribute__((ext_vector_type(8))) short short8v;
typedef __attribute__((ext_vector_type(4))) float f32x4;

// ---------------- bf16 helpers ----------------
__device__ __forceinline__ float bf_lo(unsigned u) { return __uint_as_float(u << 16); }
__device__ __forceinline__ float bf_hi(unsigned u) { return __uint_as_float(u & 0xffff0000u); }
__device__ __forceinline__ unsigned pack_bf2(float a, float b) {
  unsigned ua = __float_as_uint(a);
  ua = (ua + 0x7fffu + ((ua >> 16) & 1u)) >> 16;
  unsigned ub = __float_as_uint(b);
  ub = (ub + 0x7fffu + ((ub >> 16) & 1u)) & 0xffff0000u;
  return ua | ub;
}
__device__ __forceinline__ unsigned short bf16r(float f) {
  unsigned u = __float_as_uint(f);
  u = (u + 0x7fffu + ((u >> 16) & 1u)) >> 16;
  return (unsigned short)u;
}

// ---------------- prep0: zero counters + bf16/transposed weights ------------
__global__ void k_prep0(const float* __restrict__ W1, const float* __restrict__ W2,
                        const float* __restrict__ We,
                        unsigned short* __restrict__ W1t,
                        unsigned short* __restrict__ W2t,
                        unsigned short* __restrict__ Wabt,
                        int* cnt) {
  int i = blockIdx.x * 256 + threadIdx.x;
  if (i < NN) cnt[i] = 0;
  if (i < 8192)  { int c = i >> 6, k = i & 63;  W1t[i] = bf16r(W1[k * 128 + c]); }
  if (i < 16384) { int c = i >> 7, k = i & 127; W2t[i] = bf16r(W2[k * 128 + c]); }
  if (i < 8192) {
    int c = i >> 7, k = i & 127;
    float v = (c < 32) ? We[k * 32 + c] : We[(128 + k) * 32 + (c - 32)];
    Wabt[i] = bf16r(v);
  }
}

// ---------------- CSR build ----------------
// count + rank: rank[i] = position of edge i within its dst bucket
__global__ void k_count(const int* __restrict__ dst, int* __restrict__ cnt,
                        int* __restrict__ rank, int e) {
  int i = blockIdx.x * blockDim.x + threadIdx.x;
  if (i < e) rank[i] = atomicAdd(&cnt[dst[i]], 1);
}

__global__ void k_scan1(const int* cnt, int* offs, int* bsum, int n) {
  __shared__ int s[256];
  int i = blockIdx.x * 256 + threadIdx.x;
  int v = (i < n) ? cnt[i] : 0;
  s[threadIdx.x] = v;
  __syncthreads();
  #pragma unroll
  for (int d = 1; d < 256; d <<= 1) {
    int t = (threadIdx.x >= d) ? s[threadIdx.x - d] : 0;
    __syncthreads();
    s[threadIdx.x] += t;
    __syncthreads();
  }
  if (i < n) offs[i] = s[threadIdx.x] - v;
  if (threadIdx.x == 255) bsum[blockIdx.x] = s[255];
}

__global__ void k_scan2(int* bsum, int* offsN, int nb) {
  __shared__ int s[256];
  int v = (threadIdx.x < nb) ? bsum[threadIdx.x] : 0;
  s[threadIdx.x] = v;
  __syncthreads();
  #pragma unroll
  for (int d = 1; d < 256; d <<= 1) {
    int t = (threadIdx.x >= d) ? s[threadIdx.x - d] : 0;
    __syncthreads();
    s[threadIdx.x] += t;
    __syncthreads();
  }
  if (threadIdx.x < nb) bsum[threadIdx.x] = s[threadIdx.x] - v;
  if (threadIdx.x == 255) *offsN = s[255];
}

// fused: offs += block prefix (lane0 of each 32-group); dinv; prescale x -> bf16
// grid over NN*32 threads; group g handles node g
__global__ void k_scan3p(int* __restrict__ offs, const int* __restrict__ bsum,
                         const int* __restrict__ cnt, float* __restrict__ dinv,
                         const float* __restrict__ x, unsigned* __restrict__ xs) {
  int i = blockIdx.x * blockDim.x + threadIdx.x;
  if (i >= NN * 32) return;
  int v = i >> 5, l = i & 31;
  float d = rsqrtf((float)(cnt[v] + 1));
  if (l == 0) {
    offs[v] += bsum[v >> 8];
    dinv[v] = d;
  }
  float2 xv = ((const float2*)(x + (size_t)v * 64))[l];
  xs[(size_t)v * 32 + l] = pack_bf2(xv.x * d, xv.y * d);
}

// atomic-free fill: adj[offs[d] + rank[i]] = src[i]
__global__ void k_fill(const int* __restrict__ src, const int* __restrict__ dst,
                       const int* __restrict__ offs, const int* __restrict__ rank,
                       int* __restrict__ adj, int e) {
  int i = blockIdx.x * blockDim.x + threadIdx.x;
  if (i < e) adj[offs[dst[i]] + rank[i]] = src[i];
}

// ---------------- fused agg64 + MFMA GEMM1 ----------------------------------
// Block = 32 nodes. Phase A: aggregate z1 rows into LDS (bf16, padded).
// Phase B: h1 = bf16(dinv*relu(z1@W1+b1)) via MFMA, A-fragments from LDS.
__global__ __launch_bounds__(256) void k_aggemm1(
    const unsigned* __restrict__ xs, const int* __restrict__ offs,
    const int* __restrict__ adj, const float* __restrict__ dinv,
    const unsigned short* __restrict__ Bt,  // w1t bf16 [128c][64k]
    const float* __restrict__ bias,         // b1
    unsigned short* __restrict__ outb,      // h1s bf16 [n][128]
    int n) {
  __shared__ unsigned zd[32][36];  // 32 rows x 64 bf16, stride 144B (16B-aligned, 2-way banks)
  int lane = threadIdx.x & 63;
  int wid = threadIdx.x >> 6;
  int r0 = blockIdx.x * 32;
  // phase A: each wave aggregates 8 nodes (2 at a time via 32-lane halves)
  int h = lane >> 5, hl = lane & 31;
  for (int it = 0; it < 4; it++) {
    int loc = wid * 8 + it * 2 + h;
    int node = r0 + loc;
    if (node >= n) node = n - 1;
    float ax[8], ay[8];
    {
      unsigned u = xs[(size_t)node * 32 + hl];
      ax[0] = bf_lo(u); ay[0] = bf_hi(u);
    }
    #pragma unroll
    for (int u = 1; u < 8; u++) { ax[u] = 0.f; ay[u] = 0.f; }
    int s = offs[node], e = offs[node + 1];
    int i = s;
    for (; i + 8 <= e; i += 8) {
      int idx[8];
      #pragma unroll
      for (int u = 0; u < 8; u++) idx[u] = adj[i + u];
      #pragma unroll
      for (int u = 0; u < 8; u++) {
        unsigned uv = xs[(size_t)idx[u] * 32 + hl];
        ax[u] += bf_lo(uv); ay[u] += bf_hi(uv);
      }
    }
    for (; i < e; i++) {
      unsigned uv = xs[(size_t)adj[i] * 32 + hl];
      ax[0] += bf_lo(uv); ay[0] += bf_hi(uv);
    }
    float sx = ((ax[0] + ax[1]) + (ax[2] + ax[3])) + ((ax[4] + ax[5]) + (ax[6] + ax[7]));
    float sy = ((ay[0] + ay[1]) + (ay[2] + ay[3])) + ((ay[4] + ay[5]) + (ay[6] + ay[7]));
    float d = dinv[node];
    zd[loc][hl] = pack_bf2(sx * d, sy * d);
  }
  __syncthreads();
  // phase B: MFMA 32 rows x 128 cols, K=64
  int wr = wid >> 1, wc = wid & 1;
  int lr = lane & 15;
  int lk = (lane >> 4) * 8;
  f32x4 acc[4];
  #pragma unroll
  for (int ct = 0; ct < 4; ct++) acc[ct] = (f32x4){0.f, 0.f, 0.f, 0.f};
  #pragma unroll
  for (int ks = 0; ks < 64; ks += 32) {
    short8v a = *reinterpret_cast<const short8v*>(
        (const unsigned short*)&zd[wr * 16 + lr][0] + lk + ks);
    #pragma unroll
    for (int ct = 0; ct < 4; ct++) {
      const unsigned short* bp = Bt + (size_t)(wc * 64 + ct * 16 + lr) * 64 + lk + ks;
      short8v b = *reinterpret_cast<const short8v*>(bp);
      acc[ct] = __builtin_amdgcn_mfma_f32_16x16x32_bf16(a, b, acc[ct], 0, 0, 0);
    }
  }
  int rbase = r0 + wr * 16 + (lane >> 4) * 4;
  #pragma unroll
  for (int ct = 0; ct < 4; ct++) {
    int col = wc * 64 + ct * 16 + lr;
    float bv = bias[col];
    #pragma unroll
    for (int rg = 0; rg < 4; rg++) {
      int row = rbase + rg;
      if (row >= n) continue;
      float v = fmaxf(acc[ct][rg] + bv, 0.f);
      outb[(size_t)row * 128 + col] = bf16r(v * dinv[row]);
    }
  }
}

// ---------------- fused agg128 + MFMA GEMM2 + PQ -----------------------------
// Phase A: aggregate z2 rows (128 cols) into LDS. Phase B: h2=relu(z2@W2+b2)
// -> LDS. Phase C: PQ = h2 @ [Wa||Wb] -> bf16 global.
__global__ __launch_bounds__(256) void k_aggemm2(
    const unsigned* __restrict__ hw,        // h1s as dwords [n][64]
    const int* __restrict__ offs, const int* __restrict__ adj,
    const float* __restrict__ dinv,
    const unsigned short* __restrict__ Bt,   // w2t bf16 [128c][128k]
    const unsigned short* __restrict__ Wabt, // bf16 [64c][128k]
    const float* __restrict__ bias,          // b2
    unsigned short* __restrict__ PQb,        // bf16 [n][64]
    int n) {
  __shared__ unsigned ztd[32][68];        // 32 x 128 bf16, stride 272B
  __shared__ unsigned short hs2[32][136]; // 32 x 128 bf16 h2 tile, stride 272B
  int lane = threadIdx.x & 63;
  int wid = threadIdx.x >> 6;
  int r0 = blockIdx.x * 32;
  // phase A: each wave aggregates 8 nodes sequentially (full-wave rows)
  for (int it = 0; it < 8; it++) {
    int loc = wid * 8 + it;
    int node = r0 + loc;
    if (node >= n) node = n - 1;
    float ax[8], ay[8];
    {
      unsigned u = hw[(size_t)node * 64 + lane];
      ax[0] = bf_lo(u); ay[0] = bf_hi(u);
    }
    #pragma unroll
    for (int u = 1; u < 8; u++) { ax[u] = 0.f; ay[u] = 0.f; }
    int s = offs[node], e = offs[node + 1];
    int i = s;
    for (; i + 8 <= e; i += 8) {
      int idx[8];
      #pragma unroll
      for (int u = 0; u < 8; u++) idx[u] = adj[i + u];
      #pragma unroll
      for (int u = 0; u < 8; u++) {
        unsigned uv = hw[(size_t)idx[u] * 64 + lane];
        ax[u] += bf_lo(uv); ay[u] += bf_hi(uv);
      }
    }
    for (; i < e; i++) {
      unsigned uv = hw[(size_t)adj[i] * 64 + lane];
      ax[0] += bf_lo(uv); ay[0] += bf_hi(uv);
    }
    float sx = ((ax[0] + ax[1]) + (ax[2] + ax[3])) + ((ax[4] + ax[5]) + (ax[6] + ax[7]));
    float sy = ((ay[0] + ay[1]) + (ay[2] + ay[3])) + ((ay[4] + ay[5]) + (ay[6] + ay[7]));
    float d = dinv[node];
    ztd[loc][lane] = pack_bf2(sx * d, sy * d);
  }
  __syncthreads();
  // phase B: h2 = relu(z2 @ W2 + b2) -> hs2
  int wr = wid >> 1, wc = wid & 1;
  int lr = lane & 15;
  int lk = (lane >> 4) * 8;
  f32x4 acc[4];
  #pragma unroll
  for (int ct = 0; ct < 4; ct++) acc[ct] = (f32x4){0.f, 0.f, 0.f, 0.f};
  #pragma unroll
  for (int ks = 0; ks < 128; ks += 32) {
    short8v a = *reinterpret_cast<const short8v*>(
        (const unsigned short*)&ztd[wr * 16 + lr][0] + lk + ks);
    #pragma unroll
    for (int ct = 0; ct < 4; ct++) {
      const unsigned short* bp = Bt + (size_t)(wc * 64 + ct * 16 + lr) * 128 + lk + ks;
      short8v b = *reinterpret_cast<const short8v*>(bp);
      acc[ct] = __builtin_amdgcn_mfma_f32_16x16x32_bf16(a, b, acc[ct], 0, 0, 0);
    }
  }
  int rloc = wr * 16 + (lane >> 4) * 4;
  #pragma unroll
  for (int ct = 0; ct < 4; ct++) {
    int col = wc * 64 + ct * 16 + lr;
    float bv = bias[col];
    #pragma unroll
    for (int rg = 0; rg < 4; rg++)
      hs2[rloc + rg][col] = bf16r(fmaxf(acc[ct][rg] + bv, 0.f));
  }
  __syncthreads();
  // phase C: PQ = h2 @ [Wa||Wb], wave = 16 rows x 32 cols
  f32x4 acc2[2];
  acc2[0] = (f32x4){0.f, 0.f, 0.f, 0.f};
  acc2[1] = (f32x4){0.f, 0.f, 0.f, 0.f};
  #pragma unroll
  for (int ks = 0; ks < 128; ks += 32) {
    short8v a2 = *reinterpret_cast<const short8v*>(&hs2[wr * 16 + lr][lk + ks]);
    #pragma unroll
    for (int ct = 0; ct < 2; ct++) {
      const unsigned short* wp = Wabt + (size_t)(wc * 32 + ct * 16 + lr) * 128 + lk + ks;
      short8v b = *reinterpret_cast<const short8v*>(wp);
      acc2[ct] = __builtin_amdgcn_mfma_f32_16x16x32_bf16(a2, b, acc2[ct], 0, 0, 0);
    }
  }
  #pragma unroll
  for (int ct = 0; ct < 2; ct++) {
    int col = wc * 32 + ct * 16 + lr;
    #pragma unroll
    for (int rg = 0; rg < 4; rg++) {
      int row = r0 + wr * 16 + (lane >> 4) * 4 + rg;
      if (row < n) PQb[(size_t)row * 64 + col] = bf16r(acc2[ct][rg]);
    }
  }
}

// ---------------- edge: out[e] = P[src] + Q[dst] + ea[e]@Wc + b -------------
__global__ __launch_bounds__(256) void k_edge5(const int* __restrict__ src,
                                               const int* __restrict__ dst,
                                               const float* __restrict__ ea,
                                               const unsigned* __restrict__ PQw,
                                               const float* __restrict__ We,
                                               const float* __restrict__ be,
                                               float* __restrict__ out, int ne) {
  __shared__ int sidx[64];
  __shared__ int didx[64];
  __shared__ float eas[64][16];
  __shared__ float wcs[16][32];
  __shared__ float bes[32];
  int tid = threadIdx.x;
  int ebase = blockIdx.x * 64;  // NE % 64 == 0
  if (tid < 128)
    ((float4*)wcs)[tid] = ((const float4*)(We + 256 * 32))[tid];
  if (tid < 32) bes[tid] = be[tid];
  if (tid >= 128 && tid < 192) sidx[tid - 128] = src[ebase + tid - 128];
  if (tid >= 192)              didx[tid - 192] = dst[ebase + tid - 192];
  {
    int row = tid >> 2, q = tid & 3;
    ((float4*)eas[row])[q] = ((const float4*)(ea + (size_t)(ebase + row) * 16))[q];
  }
  __syncthreads();
  int l = tid & 15;
  int grp = tid >> 4;  // 0..15
  unsigned pw[4], qw[4];
  int el[4];
  #pragma unroll
  for (int u = 0; u < 4; u++) el[u] = u * 16 + grp;
  #pragma unroll
  for (int u = 0; u < 4; u++) {
    int s = sidx[el[u]];
    int d = didx[el[u]];
    pw[u] = PQw[(size_t)s * 32 + l];
    qw[u] = PQw[(size_t)d * 32 + 16 + l];
  }
  int c0 = 2 * l;
  #pragma unroll
  for (int u = 0; u < 4; u++) {
    int e = ebase + el[u];
    float a0 = bf_lo(pw[u]) + bf_lo(qw[u]) + bes[c0];
    float a1 = bf_hi(pw[u]) + bf_hi(qw[u]) + bes[c0 + 1];
    #pragma unroll
    for (int k = 0; k < 16; k++) {
      float ev = eas[el[u]][k];
      a0 += ev * wcs[k][c0];
      a1 += ev * wcs[k][c0 + 1];
    }
    ((float2*)(out + (size_t)e * 32))[l] = make_float2(a0, a1);
  }
}

extern "C" void kernel_launch(void* const* d_in, const int* in_sizes, int n_in,
                              void* d_out, int out_size, void* d_ws, size_t ws_size,
                              hipStream_t stream) {
  const float* x  = (const float*)d_in[0];
  const int*   ei = (const int*)d_in[1];
  const float* ea = (const float*)d_in[2];
  const float* W1 = (const float*)d_in[3];
  const float* b1 = (const float*)d_in[4];
  const float* W2 = (const float*)d_in[5];
  const float* b2 = (const float*)d_in[6];
  const float* We = (const float*)d_in[7];
  const float* be = (const float*)d_in[8];
  float* out = (float*)d_out;
  const int* src = ei;
  const int* dst = ei + NE;

  char* w = (char*)d_ws;
  auto alloc = [&](size_t b) {
    void* p = (void*)w;
    w += (b + 255) & ~(size_t)255;
    return p;
  };
  int* cnt    = (int*)alloc(NN * 4);
  int* offs   = (int*)alloc((NN + 1) * 4);
  int* bsum   = (int*)alloc(256 * 4);
  int* adj    = (int*)alloc((size_t)NE * 4);
  int* rank   = (int*)alloc((size_t)NE * 4);
  float* dinv = (float*)alloc(NN * 4);
  unsigned* xs  = (unsigned*)alloc((size_t)NN * 32 * 4);   // bf16 [NN][64]
  unsigned* h1s = (unsigned*)alloc((size_t)NN * 64 * 4);   // bf16 [NN][128]
  unsigned short* pqb  = (unsigned short*)alloc((size_t)NN * 64 * 2);
  unsigned short* w1t  = (unsigned short*)alloc(8192 * 2);  // bf16 [128c][64k]
  unsigned short* w2t  = (unsigned short*)alloc(16384 * 2); // bf16 [128c][128k]
  unsigned short* wabt = (unsigned short*)alloc(8192 * 2);  // bf16 [64c][128k]

  const int nblkN = (NN + 255) / 256;   // 196
  const int nblkE = (NE + 255) / 256;

  k_prep0<<<nblkN, 256, 0, stream>>>(W1, W2, We, w1t, w2t, wabt, cnt);
  k_count<<<nblkE, 256, 0, stream>>>(dst, cnt, rank, NE);
  k_scan1<<<nblkN, 256, 0, stream>>>(cnt, offs, bsum, NN);
  k_scan2<<<1, 256, 0, stream>>>(bsum, offs + NN, nblkN);
  k_scan3p<<<(NN * 32 + 255) / 256, 256, 0, stream>>>(offs, bsum, cnt, dinv, x, xs);
  k_fill<<<nblkE, 256, 0, stream>>>(src, dst, offs, rank, adj, NE);

  const int mgBlk = (NN + 31) / 32;  // 1563
  k_aggemm1<<<mgBlk, 256, 0, stream>>>(xs, offs, adj, dinv, w1t, b1,
                                       (unsigned short*)h1s, NN);
  k_aggemm2<<<mgBlk, 256, 0, stream>>>(h1s, offs, adj, dinv, w2t, wabt, b2,
                                       pqb, NN);
  k_edge5<<<NE / 64, 256, 0, stream>>>(src, dst, ea, (const unsigned*)pqb,
                                       We, be, out, NE);
}

// Round 12
// 231.825 us; speedup vs baseline: 15.8058x; 1.0349x over previous
//
#include <hip/hip_runtime.h>

#define NN 50000
#define NE 800000

typedef __attribute__((ext_vector_type(8))) short short8v;
typedef __attribute__((ext_vector_type(4))) float f32x4;

// ---------------- bf16 helpers ----------------
__device__ __forceinline__ float bf_lo(unsigned u) { return __uint_as_float(u << 16); }
__device__ __forceinline__ float bf_hi(unsigned u) { return __uint_as_float(u & 0xffff0000u); }
__device__ __forceinline__ unsigned pack_bf2(float a, float b) {
  unsigned ua = __float_as_uint(a);
  ua = (ua + 0x7fffu + ((ua >> 16) & 1u)) >> 16;
  unsigned ub = __float_as_uint(b);
  ub = (ub + 0x7fffu + ((ub >> 16) & 1u)) & 0xffff0000u;
  return ua | ub;
}
__device__ __forceinline__ unsigned short bf16r(float f) {
  unsigned u = __float_as_uint(f);
  u = (u + 0x7fffu + ((u >> 16) & 1u)) >> 16;
  return (unsigned short)u;
}

// ---------------- prep0: zero counters + bf16/transposed weights ------------
__global__ void k_prep0(const float* __restrict__ W1, const float* __restrict__ W2,
                        const float* __restrict__ We,
                        unsigned short* __restrict__ W1t,
                        unsigned short* __restrict__ W2t,
                        unsigned short* __restrict__ Wabt,
                        int* cnt) {
  int i = blockIdx.x * 256 + threadIdx.x;
  if (i < NN) cnt[i] = 0;
  if (i < 8192)  { int c = i >> 6, k = i & 63;  W1t[i] = bf16r(W1[k * 128 + c]); }
  if (i < 16384) { int c = i >> 7, k = i & 127; W2t[i] = bf16r(W2[k * 128 + c]); }
  if (i < 8192) {
    int c = i >> 7, k = i & 127;
    float v = (c < 32) ? We[k * 32 + c] : We[(128 + k) * 32 + (c - 32)];
    Wabt[i] = bf16r(v);
  }
}

// ---------------- CSR build ----------------
__global__ void k_count(const int* __restrict__ dst, int* __restrict__ cnt,
                        int* __restrict__ rank, int e) {
  int i = blockIdx.x * blockDim.x + threadIdx.x;
  if (i < e) rank[i] = atomicAdd(&cnt[dst[i]], 1);
}

__global__ void k_scan1(const int* cnt, int* offs, int* bsum, int n) {
  __shared__ int s[256];
  int i = blockIdx.x * 256 + threadIdx.x;
  int v = (i < n) ? cnt[i] : 0;
  s[threadIdx.x] = v;
  __syncthreads();
  #pragma unroll
  for (int d = 1; d < 256; d <<= 1) {
    int t = (threadIdx.x >= d) ? s[threadIdx.x - d] : 0;
    __syncthreads();
    s[threadIdx.x] += t;
    __syncthreads();
  }
  if (i < n) offs[i] = s[threadIdx.x] - v;
  if (threadIdx.x == 255) bsum[blockIdx.x] = s[255];
}

__global__ void k_scan2(int* bsum, int* offsN, int nb) {
  __shared__ int s[256];
  int v = (threadIdx.x < nb) ? bsum[threadIdx.x] : 0;
  s[threadIdx.x] = v;
  __syncthreads();
  #pragma unroll
  for (int d = 1; d < 256; d <<= 1) {
    int t = (threadIdx.x >= d) ? s[threadIdx.x - d] : 0;
    __syncthreads();
    s[threadIdx.x] += t;
    __syncthreads();
  }
  if (threadIdx.x < nb) bsum[threadIdx.x] = s[threadIdx.x] - v;
  if (threadIdx.x == 255) *offsN = s[255];
}

// fused: offs += block prefix; dinv; prescale x -> bf16
__global__ void k_scan3p(int* __restrict__ offs, const int* __restrict__ bsum,
                         const int* __restrict__ cnt, float* __restrict__ dinv,
                         const float* __restrict__ x, unsigned* __restrict__ xs) {
  int i = blockIdx.x * blockDim.x + threadIdx.x;
  if (i >= NN * 32) return;
  int v = i >> 5, l = i & 31;
  float d = rsqrtf((float)(cnt[v] + 1));
  if (l == 0) {
    offs[v] += bsum[v >> 8];
    dinv[v] = d;
  }
  float2 xv = ((const float2*)(x + (size_t)v * 64))[l];
  xs[(size_t)v * 32 + l] = pack_bf2(xv.x * d, xv.y * d);
}

// atomic-free fill
__global__ void k_fill(const int* __restrict__ src, const int* __restrict__ dst,
                       const int* __restrict__ offs, const int* __restrict__ rank,
                       int* __restrict__ adj, int e) {
  int i = blockIdx.x * blockDim.x + threadIdx.x;
  if (i < e) adj[offs[dst[i]] + rank[i]] = src[i];
}

// ---------------- fused agg64 + MFMA GEMM1 ----------------------------------
__global__ __launch_bounds__(256) void k_aggemm1(
    const unsigned* __restrict__ xs, const int* __restrict__ offs,
    const int* __restrict__ adj, const float* __restrict__ dinv,
    const unsigned short* __restrict__ Bt,  // w1t bf16 [128c][64k]
    const float* __restrict__ bias,         // b1
    unsigned short* __restrict__ outb,      // h1s bf16 [n][128]
    int n) {
  __shared__ unsigned zd[32][36];
  int lane = threadIdx.x & 63;
  int wid = threadIdx.x >> 6;
  int r0 = blockIdx.x * 32;
  int h = lane >> 5, hl = lane & 31;
  for (int it = 0; it < 4; it++) {
    int loc = wid * 8 + it * 2 + h;
    int node = r0 + loc;
    if (node >= n) node = n - 1;
    float ax[8], ay[8];
    {
      unsigned u = xs[(size_t)node * 32 + hl];
      ax[0] = bf_lo(u); ay[0] = bf_hi(u);
    }
    #pragma unroll
    for (int u = 1; u < 8; u++) { ax[u] = 0.f; ay[u] = 0.f; }
    int s = offs[node], e = offs[node + 1];
    int i = s;
    for (; i + 8 <= e; i += 8) {
      int idx[8];
      #pragma unroll
      for (int u = 0; u < 8; u++) idx[u] = adj[i + u];
      #pragma unroll
      for (int u = 0; u < 8; u++) {
        unsigned uv = xs[(size_t)idx[u] * 32 + hl];
        ax[u] += bf_lo(uv); ay[u] += bf_hi(uv);
      }
    }
    for (; i < e; i++) {
      unsigned uv = xs[(size_t)adj[i] * 32 + hl];
      ax[0] += bf_lo(uv); ay[0] += bf_hi(uv);
    }
    float sx = ((ax[0] + ax[1]) + (ax[2] + ax[3])) + ((ax[4] + ax[5]) + (ax[6] + ax[7]));
    float sy = ((ay[0] + ay[1]) + (ay[2] + ay[3])) + ((ay[4] + ay[5]) + (ay[6] + ay[7]));
    float d = dinv[node];
    zd[loc][hl] = pack_bf2(sx * d, sy * d);
  }
  __syncthreads();
  int wr = wid >> 1, wc = wid & 1;
  int lr = lane & 15;
  int lk = (lane >> 4) * 8;
  f32x4 acc[4];
  #pragma unroll
  for (int ct = 0; ct < 4; ct++) acc[ct] = (f32x4){0.f, 0.f, 0.f, 0.f};
  #pragma unroll
  for (int ks = 0; ks < 64; ks += 32) {
    short8v a = *reinterpret_cast<const short8v*>(
        (const unsigned short*)&zd[wr * 16 + lr][0] + lk + ks);
    #pragma unroll
    for (int ct = 0; ct < 4; ct++) {
      const unsigned short* bp = Bt + (size_t)(wc * 64 + ct * 16 + lr) * 64 + lk + ks;
      short8v b = *reinterpret_cast<const short8v*>(bp);
      acc[ct] = __builtin_amdgcn_mfma_f32_16x16x32_bf16(a, b, acc[ct], 0, 0, 0);
    }
  }
  int rbase = r0 + wr * 16 + (lane >> 4) * 4;
  #pragma unroll
  for (int ct = 0; ct < 4; ct++) {
    int col = wc * 64 + ct * 16 + lr;
    float bv = bias[col];
    #pragma unroll
    for (int rg = 0; rg < 4; rg++) {
      int row = rbase + rg;
      if (row >= n) continue;
      float v = fmaxf(acc[ct][rg] + bv, 0.f);
      outb[(size_t)row * 128 + col] = bf16r(v * dinv[row]);
    }
  }
}

// ---------------- agg128: z[v] = bf16(dinv[v]*(hs[v] + sum hs[src])) --------
// one wave per node; 16-deep gather unroll (16 lines in flight)
__global__ void k_agg128(const unsigned* __restrict__ hs,
                         const int* __restrict__ offs, const int* __restrict__ adj,
                         const float* __restrict__ dinv, unsigned* __restrict__ z,
                         int n) {
  int node = blockIdx.x * 4 + (threadIdx.x >> 6);
  if (node >= n) return;
  int lane = threadIdx.x & 63;
  float ax[8], ay[8];
  {
    unsigned u = hs[(size_t)node * 64 + lane];
    ax[0] = bf_lo(u); ay[0] = bf_hi(u);
  }
  #pragma unroll
  for (int u = 1; u < 8; u++) { ax[u] = 0.f; ay[u] = 0.f; }
  int s = offs[node], e = offs[node + 1];
  int i = s;
  for (; i + 16 <= e; i += 16) {
    int idx[16];
    #pragma unroll
    for (int u = 0; u < 16; u++) idx[u] = adj[i + u];
    unsigned uv[16];
    #pragma unroll
    for (int u = 0; u < 16; u++) uv[u] = hs[(size_t)idx[u] * 64 + lane];
    #pragma unroll
    for (int u = 0; u < 16; u++) {
      ax[u & 7] += bf_lo(uv[u]); ay[u & 7] += bf_hi(uv[u]);
    }
  }
  for (; i + 8 <= e; i += 8) {
    int idx[8];
    #pragma unroll
    for (int u = 0; u < 8; u++) idx[u] = adj[i + u];
    #pragma unroll
    for (int u = 0; u < 8; u++) {
      unsigned uv = hs[(size_t)idx[u] * 64 + lane];
      ax[u] += bf_lo(uv); ay[u] += bf_hi(uv);
    }
  }
  for (; i < e; i++) {
    unsigned uv = hs[(size_t)adj[i] * 64 + lane];
    ax[0] += bf_lo(uv); ay[0] += bf_hi(uv);
  }
  float sx = ((ax[0] + ax[1]) + (ax[2] + ax[3])) + ((ax[4] + ax[5]) + (ax[6] + ax[7]));
  float sy = ((ay[0] + ay[1]) + (ay[2] + ay[3])) + ((ay[4] + ay[5]) + (ay[6] + ay[7]));
  float d = dinv[node];
  z[(size_t)node * 64 + lane] = pack_bf2(sx * d, sy * d);
}

// ---------------- MFMA GEMM layer2 + fused PQ --------------------------------
__global__ __launch_bounds__(256) void k_mgemm2pq(
    const unsigned short* __restrict__ A,    // z2 bf16 [n][128]
    const unsigned short* __restrict__ Bt,   // W2t bf16 [128c][128k]
    const unsigned short* __restrict__ Wabt, // bf16 [64c][128k]
    const float* __restrict__ bias,          // b2
    unsigned short* __restrict__ PQb,        // bf16 [n][64]
    int n) {
  __shared__ unsigned short hs[32][136];
  int lane = threadIdx.x & 63;
  int wid = threadIdx.x >> 6;
  int wr = wid >> 1, wc = wid & 1;
  int r0 = blockIdx.x * 32;
  int lr = lane & 15;
  int lk = (lane >> 4) * 8;
  int arow = r0 + wr * 16 + lr;
  if (arow >= n) arow = n - 1;
  const unsigned short* arp = A + (size_t)arow * 128 + lk;
  f32x4 acc[4];
  #pragma unroll
  for (int ct = 0; ct < 4; ct++) acc[ct] = (f32x4){0.f, 0.f, 0.f, 0.f};
  #pragma unroll
  for (int ks = 0; ks < 128; ks += 32) {
    short8v a = *reinterpret_cast<const short8v*>(arp + ks);
    #pragma unroll
    for (int ct = 0; ct < 4; ct++) {
      const unsigned short* bp = Bt + (size_t)(wc * 64 + ct * 16 + lr) * 128 + lk + ks;
      short8v b = *reinterpret_cast<const short8v*>(bp);
      acc[ct] = __builtin_amdgcn_mfma_f32_16x16x32_bf16(a, b, acc[ct], 0, 0, 0);
    }
  }
  int rloc = wr * 16 + (lane >> 4) * 4;
  #pragma unroll
  for (int ct = 0; ct < 4; ct++) {
    int col = wc * 64 + ct * 16 + lr;
    float bv = bias[col];
    #pragma unroll
    for (int rg = 0; rg < 4; rg++)
      hs[rloc + rg][col] = bf16r(fmaxf(acc[ct][rg] + bv, 0.f));
  }
  __syncthreads();
  f32x4 acc2[2];
  acc2[0] = (f32x4){0.f, 0.f, 0.f, 0.f};
  acc2[1] = (f32x4){0.f, 0.f, 0.f, 0.f};
  #pragma unroll
  for (int ks = 0; ks < 128; ks += 32) {
    short8v a2 = *reinterpret_cast<const short8v*>(&hs[wr * 16 + lr][lk + ks]);
    #pragma unroll
    for (int ct = 0; ct < 2; ct++) {
      const unsigned short* wp = Wabt + (size_t)(wc * 32 + ct * 16 + lr) * 128 + lk + ks;
      short8v b = *reinterpret_cast<const short8v*>(wp);
      acc2[ct] = __builtin_amdgcn_mfma_f32_16x16x32_bf16(a2, b, acc2[ct], 0, 0, 0);
    }
  }
  #pragma unroll
  for (int ct = 0; ct < 2; ct++) {
    int col = wc * 32 + ct * 16 + lr;
    #pragma unroll
    for (int rg = 0; rg < 4; rg++) {
      int row = r0 + wr * 16 + (lane >> 4) * 4 + rg;
      if (row < n) PQb[(size_t)row * 64 + col] = bf16r(acc2[ct][rg]);
    }
  }
}

// ---------------- edge: 128 edges/block, 8 edges/thread, 16 gathers in flight
__global__ __launch_bounds__(256) void k_edge6(const int* __restrict__ src,
                                               const int* __restrict__ dst,
                                               const float* __restrict__ ea,
                                               const unsigned* __restrict__ PQw,
                                               const float* __restrict__ We,
                                               const float* __restrict__ be,
                                               float* __restrict__ out, int ne) {
  __shared__ int sidx[128];
  __shared__ int didx[128];
  __shared__ float eas[128][16];
  __shared__ float wcs[16][32];
  __shared__ float bes[32];
  int tid = threadIdx.x;
  int ebase = blockIdx.x * 128;  // NE % 128 == 0
  if (tid < 128) {
    ((float4*)wcs)[tid] = ((const float4*)(We + 256 * 32))[tid];
    sidx[tid] = src[ebase + tid];
  } else {
    didx[tid - 128] = dst[ebase + tid - 128];
  }
  if (tid < 32) bes[tid] = be[tid];
  #pragma unroll
  for (int j = 0; j < 2; j++) {
    int q4 = tid * 2 + j;           // 0..511
    int row = q4 >> 2, q = q4 & 3;
    ((float4*)eas[row])[q] = ((const float4*)(ea + (size_t)(ebase + row) * 16))[q];
  }
  __syncthreads();
  int l = tid & 15;
  int grp = tid >> 4;  // 0..15
  unsigned pw[8], qw[8];
  #pragma unroll
  for (int u = 0; u < 8; u++) {
    int el = u * 16 + grp;
    int s = sidx[el];
    int d = didx[el];
    pw[u] = PQw[(size_t)s * 32 + l];
    qw[u] = PQw[(size_t)d * 32 + 16 + l];
  }
  int c0 = 2 * l;
  #pragma unroll
  for (int u = 0; u < 8; u++) {
    int el = u * 16 + grp;
    int e = ebase + el;
    float a0 = bf_lo(pw[u]) + bf_lo(qw[u]) + bes[c0];
    float a1 = bf_hi(pw[u]) + bf_hi(qw[u]) + bes[c0 + 1];
    #pragma unroll
    for (int k = 0; k < 16; k++) {
      float ev = eas[el][k];
      a0 += ev * wcs[k][c0];
      a1 += ev * wcs[k][c0 + 1];
    }
    ((float2*)(out + (size_t)e * 32))[l] = make_float2(a0, a1);
  }
}

extern "C" void kernel_launch(void* const* d_in, const int* in_sizes, int n_in,
                              void* d_out, int out_size, void* d_ws, size_t ws_size,
                              hipStream_t stream) {
  const float* x  = (const float*)d_in[0];
  const int*   ei = (const int*)d_in[1];
  const float* ea = (const float*)d_in[2];
  const float* W1 = (const float*)d_in[3];
  const float* b1 = (const float*)d_in[4];
  const float* W2 = (const float*)d_in[5];
  const float* b2 = (const float*)d_in[6];
  const float* We = (const float*)d_in[7];
  const float* be = (const float*)d_in[8];
  float* out = (float*)d_out;
  const int* src = ei;
  const int* dst = ei + NE;

  char* w = (char*)d_ws;
  auto alloc = [&](size_t b) {
    void* p = (void*)w;
    w += (b + 255) & ~(size_t)255;
    return p;
  };
  int* cnt    = (int*)alloc(NN * 4);
  int* offs   = (int*)alloc((NN + 1) * 4);
  int* bsum   = (int*)alloc(256 * 4);
  int* adj    = (int*)alloc((size_t)NE * 4);
  int* rank   = (int*)alloc((size_t)NE * 4);
  float* dinv = (float*)alloc(NN * 4);
  unsigned* xs  = (unsigned*)alloc((size_t)NN * 32 * 4);   // bf16 [NN][64]
  unsigned* h1s = (unsigned*)alloc((size_t)NN * 64 * 4);   // bf16 [NN][128]
  unsigned* z12 = (unsigned*)alloc((size_t)NN * 64 * 4);   // bf16 z2 [NN][128]
  unsigned short* w1t  = (unsigned short*)alloc(8192 * 2);
  unsigned short* w2t  = (unsigned short*)alloc(16384 * 2);
  unsigned short* wabt = (unsigned short*)alloc(8192 * 2);
  unsigned short* pqb = (unsigned short*)h1s;  // reuse: h1s dead after agg128

  const int nblkN = (NN + 255) / 256;   // 196
  const int nblkE = (NE + 255) / 256;

  k_prep0<<<nblkN, 256, 0, stream>>>(W1, W2, We, w1t, w2t, wabt, cnt);
  k_count<<<nblkE, 256, 0, stream>>>(dst, cnt, rank, NE);
  k_scan1<<<nblkN, 256, 0, stream>>>(cnt, offs, bsum, NN);
  k_scan2<<<1, 256, 0, stream>>>(bsum, offs + NN, nblkN);
  k_scan3p<<<(NN * 32 + 255) / 256, 256, 0, stream>>>(offs, bsum, cnt, dinv, x, xs);
  k_fill<<<nblkE, 256, 0, stream>>>(src, dst, offs, rank, adj, NE);

  const int mgBlk = (NN + 31) / 32;  // 1563
  k_aggemm1<<<mgBlk, 256, 0, stream>>>(xs, offs, adj, dinv, w1t, b1,
                                       (unsigned short*)h1s, NN);
  k_agg128<<<(NN + 3) / 4, 256, 0, stream>>>(h1s, offs, adj, dinv, z12, NN);
  k_mgemm2pq<<<mgBlk, 256, 0, stream>>>((const unsigned short*)z12, w2t, wabt,
                                        b2, pqb, NN);
  k_edge6<<<NE / 128, 256, 0, stream>>>(src, dst, ea, (const unsigned*)pqb,
                                        We, be, out, NE);
}